// Round 3
// baseline (1491.679 us; speedup 1.0000x reference)
//
#include <hip/hip_runtime.h>
#include <hip/hip_bf16.h>

typedef __bf16 bf16;
typedef __attribute__((ext_vector_type(8))) __bf16 bf16x8;
typedef __attribute__((ext_vector_type(4))) float f32x4;

// Pack B1 = [W1l | W1r] as [128 cols][128 k] bf16 (K-major, i.e. B^T form),
//      B2 = [W2l ; W2r] as [128 cols][128 k] bf16.
__global__ __launch_bounds__(256) void build_B_k(const float* __restrict__ W1l,
                                                 const float* __restrict__ W1r,
                                                 const float* __restrict__ W2l,
                                                 const float* __restrict__ W2r,
                                                 bf16* __restrict__ B1,
                                                 bf16* __restrict__ B2) {
  int gid = blockIdx.x * 256 + threadIdx.x;  // 0..32767
  if (gid < 16384) {
    int c = gid >> 7, k = gid & 127;
    float v = (k < 64) ? W1l[c * 64 + k] : W1r[c * 64 + (k - 64)];
    B1[gid] = (bf16)v;
  } else {
    int idx = gid - 16384;
    int n = idx >> 7, k = idx & 127;
    float v = (n < 64) ? W2l[n * 128 + k] : W2r[(n - 64) * 128 + k];
    B2[idx] = (bf16)v;
  }
}

// ---- bucket sort of edges by dst>>7 (128 nodes per bucket) ----

// Pass A: per-block LDS histogram, flush with global atomics.
__global__ __launch_bounds__(256) void bhist_k(const int* __restrict__ dst,
                                               int* __restrict__ bcnt, int E, int nb) {
  __shared__ int h[1024];
  for (int i = threadIdx.x; i < 1024; i += 256) h[i] = 0;
  __syncthreads();
  for (long e = (long)blockIdx.x * 256 + threadIdx.x; e < E; e += (long)gridDim.x * 256)
    atomicAdd(&h[dst[e] >> 7], 1);
  __syncthreads();
  for (int i = threadIdx.x; i < nb; i += 256)
    if (h[i]) atomicAdd(&bcnt[i], h[i]);
}

// Pass B: single-block exclusive scan of bucket counts (nb <= 1024); init cursors.
__global__ __launch_bounds__(1024) void bscan_k(const int* __restrict__ bcnt,
                                                int* __restrict__ boff,
                                                int* __restrict__ bcur, int nb, int E) {
  __shared__ int sd[1024];
  int t = threadIdx.x;
  int v = (t < nb) ? bcnt[t] : 0;
  sd[t] = v;
  __syncthreads();
#pragma unroll
  for (int off = 1; off < 1024; off <<= 1) {
    int tv = (t >= off) ? sd[t - off] : 0;
    __syncthreads();
    if (t >= off) sd[t] += tv;
    __syncthreads();
  }
  if (t < nb) {
    int ex = sd[t] - v;
    boff[t] = ex;
    bcur[t] = ex;
  }
  if (t == 0) boff[nb] = E;
}

// Pass C: scatter packed (src, local-dst) records into bucket regions.
// 782 sequential write streams -> cache lines fill fully, ~no write amplification.
__global__ __launch_bounds__(256) void bfill_k(const int* __restrict__ src,
                                               const int* __restrict__ dst,
                                               int* __restrict__ bcur,
                                               uint2* __restrict__ ebuf, int E) {
  int e = blockIdx.x * 256 + threadIdx.x;
  if (e >= E) return;
  int d = dst[e];
  int pos = atomicAdd(&bcur[d >> 7], 1);
  ebuf[pos] = make_uint2((unsigned)src[e], (unsigned)(d & 127));
}

// ---- layer 1: edge-parallel mean-aggregate into LDS + build A1 = [mean | x] ----
__global__ __launch_bounds__(256) void agg1_k(const float* __restrict__ x,
                                              const int* __restrict__ boff,
                                              const uint2* __restrict__ ebuf,
                                              bf16* __restrict__ A1,
                                              float* __restrict__ degf, int N) {
  __shared__ float acc[128][64];
  __shared__ int ideg[128];
  int t = threadIdx.x, wave = t >> 6, lane = t & 63;
  for (int i = t; i < 128 * 64; i += 256) ((float*)acc)[i] = 0.0f;
  for (int i = t; i < 128; i += 256) ideg[i] = 0;
  __syncthreads();

  int b = blockIdx.x;
  int s = boff[b], e = boff[b + 1];
  int i = s + wave;
  for (; i + 12 < e; i += 16) {
    uint2 e0 = ebuf[i], e1 = ebuf[i + 4], e2 = ebuf[i + 8], e3 = ebuf[i + 12];
    float v0 = x[(long)e0.x * 64 + lane];
    float v1 = x[(long)e1.x * 64 + lane];
    float v2 = x[(long)e2.x * 64 + lane];
    float v3 = x[(long)e3.x * 64 + lane];
    atomicAdd(&acc[e0.y][lane], v0);
    atomicAdd(&acc[e1.y][lane], v1);
    atomicAdd(&acc[e2.y][lane], v2);
    atomicAdd(&acc[e3.y][lane], v3);
    if (lane == 0) {
      atomicAdd(&ideg[e0.y], 1);
      atomicAdd(&ideg[e1.y], 1);
      atomicAdd(&ideg[e2.y], 1);
      atomicAdd(&ideg[e3.y], 1);
    }
  }
  for (; i < e; i += 4) {
    uint2 er = ebuf[i];
    atomicAdd(&acc[er.y][lane], x[(long)er.x * 64 + lane]);
    if (lane == 0) atomicAdd(&ideg[er.y], 1);
  }
  __syncthreads();

  for (int lr = wave; lr < 128; lr += 4) {
    int n = b * 128 + lr;
    int d = ideg[lr];
    float mean = acc[lr][lane] / fmaxf((float)d, 1.0f);  // pads: acc==0 -> 0
    float root = (n < N) ? x[(long)n * 64 + lane] : 0.0f;
    A1[(long)n * 128 + lane] = (bf16)mean;
    A1[(long)n * 128 + 64 + lane] = (bf16)root;
    if (lane == 0) degf[n] = (float)d;
  }
}

// C[Mp x 128] = A[Mp x 128] * B^T, B stored [128 cols][128 k] bf16.
__global__ __launch_bounds__(256) void gemm_bf16_k(const bf16* __restrict__ A,
                                                   const bf16* __restrict__ B,
                                                   bf16* __restrict__ C,
                                                   const float* __restrict__ bias,
                                                   int relu) {
  int wave = threadIdx.x >> 6;
  int lane = threadIdx.x & 63;
  int row = lane & 15;
  int quad = lane >> 4;
  long mbase = (long)blockIdx.x * 128 + (long)wave * 32;

  bf16x8 bfrag[8][4];
#pragma unroll
  for (int j = 0; j < 8; j++)
#pragma unroll
    for (int s = 0; s < 4; s++)
      bfrag[j][s] = *(const bf16x8*)(B + (long)(j * 16 + row) * 128 + s * 32 + quad * 8);

  f32x4 acc[2][8] = {};
#pragma unroll
  for (int s = 0; s < 4; s++) {
    bf16x8 a0 = *(const bf16x8*)(A + (mbase + row) * 128 + s * 32 + quad * 8);
    bf16x8 a1 = *(const bf16x8*)(A + (mbase + 16 + row) * 128 + s * 32 + quad * 8);
#pragma unroll
    for (int j = 0; j < 8; j++) {
      acc[0][j] = __builtin_amdgcn_mfma_f32_16x16x32_bf16(a0, bfrag[j][s], acc[0][j], 0, 0, 0);
      acc[1][j] = __builtin_amdgcn_mfma_f32_16x16x32_bf16(a1, bfrag[j][s], acc[1][j], 0, 0, 0);
    }
  }

#pragma unroll
  for (int r = 0; r < 2; r++) {
    long rb = mbase + r * 16;
#pragma unroll
    for (int j = 0; j < 8; j++) {
      int col = j * 16 + row;
      float bv = bias ? bias[col] : 0.0f;
#pragma unroll
      for (int i = 0; i < 4; i++) {
        float v = acc[r][j][i] + bv;
        if (relu) v = v > 0.0f ? v : 0.0f;
        C[(rb + quad * 4 + i) * 128 + col] = (bf16)v;
      }
    }
  }
}

// ---- layer 2: edge-parallel aggregate of tu[:, :64] + bias + root + output ----
__global__ __launch_bounds__(256) void agg2_k(const bf16* __restrict__ tu,
                                              const int* __restrict__ boff,
                                              const uint2* __restrict__ ebuf,
                                              const float* __restrict__ degf,
                                              const float* __restrict__ b2l,
                                              float* __restrict__ out, int N) {
  __shared__ float acc[128][64];
  int t = threadIdx.x, wave = t >> 6, lane = t & 63;
  for (int i = t; i < 128 * 64; i += 256) ((float*)acc)[i] = 0.0f;
  __syncthreads();

  int b = blockIdx.x;
  int s = boff[b], e = boff[b + 1];
  int i = s + wave;
  for (; i + 12 < e; i += 16) {
    uint2 e0 = ebuf[i], e1 = ebuf[i + 4], e2 = ebuf[i + 8], e3 = ebuf[i + 12];
    float v0 = (float)tu[(long)e0.x * 128 + lane];
    float v1 = (float)tu[(long)e1.x * 128 + lane];
    float v2 = (float)tu[(long)e2.x * 128 + lane];
    float v3 = (float)tu[(long)e3.x * 128 + lane];
    atomicAdd(&acc[e0.y][lane], v0);
    atomicAdd(&acc[e1.y][lane], v1);
    atomicAdd(&acc[e2.y][lane], v2);
    atomicAdd(&acc[e3.y][lane], v3);
  }
  for (; i < e; i += 4) {
    uint2 er = ebuf[i];
    atomicAdd(&acc[er.y][lane], (float)tu[(long)er.x * 128 + lane]);
  }
  __syncthreads();

  float bv = b2l[lane];
  for (int lr = wave; lr < 128; lr += 4) {
    int n = b * 128 + lr;
    if (n >= N) continue;
    out[(long)n * 64 + lane] =
        acc[lr][lane] / fmaxf(degf[n], 1.0f) + bv + (float)tu[(long)n * 128 + 64 + lane];
  }
}

static inline size_t align256(size_t x) { return (x + 255) / 256 * 256; }

extern "C" void kernel_launch(void* const* d_in, const int* in_sizes, int n_in,
                              void* d_out, int out_size, void* d_ws, size_t ws_size,
                              hipStream_t stream) {
  const float* x = (const float*)d_in[0];
  const int* edge_index = (const int*)d_in[1];
  const float* W1l = (const float*)d_in[2];
  const float* b1l = (const float*)d_in[3];
  const float* W1r = (const float*)d_in[4];
  const float* W2l = (const float*)d_in[5];
  const float* b2l = (const float*)d_in[6];
  const float* W2r = (const float*)d_in[7];

  const int N = in_sizes[0] / 64;        // 100000
  const int E = in_sizes[1] / 2;         // 1200000
  const int Np = (N + 127) / 128 * 128;  // 100096
  const int nb = Np / 128;               // 782 buckets

  const int* src = edge_index;
  const int* dst = edge_index + E;

  char* ws = (char*)d_ws;
  size_t off = 0;
  int* bcnt = (int*)(ws + off);     off += align256((size_t)nb * 4);
  int* boff = (int*)(ws + off);     off += align256((size_t)(nb + 1) * 4);
  int* bcur = (int*)(ws + off);     off += align256((size_t)nb * 4);
  uint2* ebuf = (uint2*)(ws + off); off += align256((size_t)E * 8);
  float* degf = (float*)(ws + off); off += align256((size_t)Np * 4);
  bf16* A1 = (bf16*)(ws + off);     // reused as tu after gemm2
  bf16* tu = (bf16*)(ws + off);     off += align256((size_t)Np * 128 * 2);
  bf16* h = (bf16*)(ws + off);      off += align256((size_t)Np * 128 * 2);
  bf16* B1 = (bf16*)(ws + off);     off += align256(128 * 128 * 2);
  bf16* B2 = (bf16*)(ws + off);     off += align256(128 * 128 * 2);
  float* out = (float*)d_out;

  hipMemsetAsync(bcnt, 0, (size_t)nb * 4, stream);

  build_B_k<<<128, 256, 0, stream>>>(W1l, W1r, W2l, W2r, B1, B2);
  bhist_k<<<128, 256, 0, stream>>>(dst, bcnt, E, nb);
  bscan_k<<<1, 1024, 0, stream>>>(bcnt, boff, bcur, nb, E);
  bfill_k<<<(E + 255) / 256, 256, 0, stream>>>(src, dst, bcur, ebuf, E);

  agg1_k<<<nb, 256, 0, stream>>>(x, boff, ebuf, A1, degf, N);
  gemm_bf16_k<<<Np / 128, 256, 0, stream>>>(A1, B1, h, b1l, 1);
  gemm_bf16_k<<<Np / 128, 256, 0, stream>>>(h, B2, tu, nullptr, 0);
  agg2_k<<<nb, 256, 0, stream>>>(tu, boff, ebuf, degf, b2l, out, N);
}

// Round 4
// 596.635 us; speedup vs baseline: 2.5002x; 2.5002x over previous
//
#include <hip/hip_runtime.h>
#include <hip/hip_bf16.h>

typedef __bf16 bf16;
typedef __attribute__((ext_vector_type(8))) __bf16 bf16x8;
typedef __attribute__((ext_vector_type(4))) float f32x4;

// Pack B1 = [W1l | W1r] as [128 cols][128 k] bf16 (K-major, i.e. B^T form),
//      B2 = [W2l ; W2r] as [128 cols][128 k] bf16.
__global__ __launch_bounds__(256) void build_B_k(const float* __restrict__ W1l,
                                                 const float* __restrict__ W1r,
                                                 const float* __restrict__ W2l,
                                                 const float* __restrict__ W2r,
                                                 bf16* __restrict__ B1,
                                                 bf16* __restrict__ B2) {
  int gid = blockIdx.x * 256 + threadIdx.x;  // 0..32767
  if (gid < 16384) {
    int c = gid >> 7, k = gid & 127;
    float v = (k < 64) ? W1l[c * 64 + k] : W1r[c * 64 + (k - 64)];
    B1[gid] = (bf16)v;
  } else {
    int idx = gid - 16384;
    int n = idx >> 7, k = idx & 127;
    float v = (n < 64) ? W2l[n * 128 + k] : W2r[(n - 64) * 128 + k];
    B2[idx] = (bf16)v;
  }
}

// x (N x 64 f32) -> xb (Np x 64 bf16), zero-padded rows N..Np
__global__ __launch_bounds__(256) void cvt_k(const float* __restrict__ x,
                                             bf16* __restrict__ xb, int N, int Np) {
  int gid = blockIdx.x * 256 + threadIdx.x;  // one per 4 elems
  long base = (long)gid * 4;
  if (base >= (long)Np * 64) return;
  if (base < (long)N * 64) {
    f32x4 v = *(const f32x4*)(x + base);
    bf16 o[4] = {(bf16)v.x, (bf16)v.y, (bf16)v.z, (bf16)v.w};
    *(ulong1*)(xb + base) = *(ulong1*)o;
  } else {
    bf16 o[4] = {(bf16)0.0f, (bf16)0.0f, (bf16)0.0f, (bf16)0.0f};
    *(ulong1*)(xb + base) = *(ulong1*)o;
  }
}

// ---- bucket sort of edges by dst>>7 (128 nodes per bucket) ----
__global__ __launch_bounds__(256) void bhist_k(const int* __restrict__ dst,
                                               int* __restrict__ bcnt, int E, int nb) {
  __shared__ int h[1024];
  for (int i = threadIdx.x; i < 1024; i += 256) h[i] = 0;
  __syncthreads();
  for (long e = (long)blockIdx.x * 256 + threadIdx.x; e < E; e += (long)gridDim.x * 256)
    atomicAdd(&h[dst[e] >> 7], 1);
  __syncthreads();
  for (int i = threadIdx.x; i < nb; i += 256)
    if (h[i]) atomicAdd(&bcnt[i], h[i]);
}

__global__ __launch_bounds__(1024) void bscan_k(const int* __restrict__ bcnt,
                                                int* __restrict__ boff,
                                                int* __restrict__ bcur, int nb, int E) {
  __shared__ int sd[1024];
  int t = threadIdx.x;
  int v = (t < nb) ? bcnt[t] : 0;
  sd[t] = v;
  __syncthreads();
#pragma unroll
  for (int off = 1; off < 1024; off <<= 1) {
    int tv = (t >= off) ? sd[t - off] : 0;
    __syncthreads();
    if (t >= off) sd[t] += tv;
    __syncthreads();
  }
  if (t < nb) {
    int ex = sd[t] - v;
    boff[t] = ex;
    bcur[t] = ex;
  }
  if (t == 0) boff[nb] = E;
}

// scatter packed (src, local-dst) into bucket regions (782 sequential streams)
__global__ __launch_bounds__(256) void bfill_k(const int* __restrict__ src,
                                               const int* __restrict__ dst,
                                               int* __restrict__ bcur,
                                               uint2* __restrict__ ebuf, int E) {
  int e = blockIdx.x * 256 + threadIdx.x;
  if (e >= E) return;
  int d = dst[e];
  int pos = atomicAdd(&bcur[d >> 7], 1);
  ebuf[pos] = make_uint2((unsigned)src[e], (unsigned)(d & 127));
}

// per-bucket LDS counting sort -> node-ordered nbr + rowptr.
// Writes stay inside the bucket's contiguous region -> no write amplification.
__global__ __launch_bounds__(256) void csr_k(const uint2* __restrict__ ebuf,
                                             const int* __restrict__ boff,
                                             int* __restrict__ rowptr,
                                             int* __restrict__ nbr, int Np, int E) {
  __shared__ int hcnt[128];
  __shared__ int hoff[128];
  int b = blockIdx.x, t = threadIdx.x;
  int s = boff[b], e = boff[b + 1];
  if (t < 128) hcnt[t] = 0;
  __syncthreads();
  for (int i = s + t; i < e; i += 256) atomicAdd(&hcnt[ebuf[i].y], 1);
  __syncthreads();
  if (t < 128) hoff[t] = hcnt[t];
  __syncthreads();
#pragma unroll
  for (int off = 1; off < 128; off <<= 1) {
    int v = (t < 128 && t >= off) ? hoff[t - off] : 0;
    __syncthreads();
    if (t < 128 && t >= off) hoff[t] += v;
    __syncthreads();
  }
  if (t < 128) {
    int ex = hoff[t] - hcnt[t];  // exclusive scan
    rowptr[b * 128 + t] = s + ex;
    hcnt[t] = ex;  // becomes relative cursor
  }
  if (blockIdx.x == gridDim.x - 1 && t == 0) rowptr[Np] = E;
  __syncthreads();
  for (int i = s + t; i < e; i += 256) {
    uint2 r = ebuf[i];
    int pos = atomicAdd(&hcnt[r.y], 1);
    nbr[s + pos] = (int)r.x;
  }
}

// ---- layer 1: wave per node, bf16 gathers; A1[n] = [mean(xb[nbr]) | xb[n]] ----
__global__ __launch_bounds__(256) void agg1_k(const bf16* __restrict__ xb,
                                              const int* __restrict__ rowptr,
                                              const int* __restrict__ nbr,
                                              bf16* __restrict__ A1, int Np) {
  int wave = threadIdx.x >> 6, lane = threadIdx.x & 63;
  int n = blockIdx.x * 4 + wave;
  if (n >= Np) return;
  int s = rowptr[n], e = rowptr[n + 1];
  float sum = 0.0f;
  int i = s;
  for (; i + 3 < e; i += 4) {
    int j0 = nbr[i], j1 = nbr[i + 1], j2 = nbr[i + 2], j3 = nbr[i + 3];
    float v0 = (float)xb[(long)j0 * 64 + lane];
    float v1 = (float)xb[(long)j1 * 64 + lane];
    float v2 = (float)xb[(long)j2 * 64 + lane];
    float v3 = (float)xb[(long)j3 * 64 + lane];
    sum += (v0 + v1) + (v2 + v3);
  }
  for (; i < e; i++) sum += (float)xb[(long)nbr[i] * 64 + lane];
  float mean = sum / fmaxf((float)(e - s), 1.0f);
  A1[(long)n * 128 + lane] = (bf16)mean;
  A1[(long)n * 128 + 64 + lane] = xb[(long)n * 64 + lane];  // pads: xb==0
}

// C[Mp x 128] = A[Mp x 128] * B^T, B stored [128 cols][128 k] bf16.
// If Cu != null: cols 0..63 -> Ct (ld 64), cols 64..127 -> Cu (ld 64).
__global__ __launch_bounds__(256) void gemm_bf16_k(const bf16* __restrict__ A,
                                                   const bf16* __restrict__ B,
                                                   bf16* __restrict__ Ct,
                                                   bf16* __restrict__ Cu,
                                                   const float* __restrict__ bias,
                                                   int relu) {
  int wave = threadIdx.x >> 6;
  int lane = threadIdx.x & 63;
  int row = lane & 15;
  int quad = lane >> 4;
  long mbase = (long)blockIdx.x * 128 + (long)wave * 32;

  bf16x8 bfrag[8][4];
#pragma unroll
  for (int j = 0; j < 8; j++)
#pragma unroll
    for (int s = 0; s < 4; s++)
      bfrag[j][s] = *(const bf16x8*)(B + (long)(j * 16 + row) * 128 + s * 32 + quad * 8);

  f32x4 acc[2][8] = {};
#pragma unroll
  for (int s = 0; s < 4; s++) {
    bf16x8 a0 = *(const bf16x8*)(A + (mbase + row) * 128 + s * 32 + quad * 8);
    bf16x8 a1 = *(const bf16x8*)(A + (mbase + 16 + row) * 128 + s * 32 + quad * 8);
#pragma unroll
    for (int j = 0; j < 8; j++) {
      acc[0][j] = __builtin_amdgcn_mfma_f32_16x16x32_bf16(a0, bfrag[j][s], acc[0][j], 0, 0, 0);
      acc[1][j] = __builtin_amdgcn_mfma_f32_16x16x32_bf16(a1, bfrag[j][s], acc[1][j], 0, 0, 0);
    }
  }

#pragma unroll
  for (int r = 0; r < 2; r++) {
    long rb = mbase + r * 16;
#pragma unroll
    for (int j = 0; j < 8; j++) {
      int col = j * 16 + row;
      float bv = bias ? bias[col] : 0.0f;
#pragma unroll
      for (int i = 0; i < 4; i++) {
        float v = acc[r][j][i] + bv;
        if (relu) v = v > 0.0f ? v : 0.0f;
        long mrow = rb + quad * 4 + i;
        if (Cu) {
          if (col < 64) Ct[mrow * 64 + col] = (bf16)v;
          else Cu[mrow * 64 + (col - 64)] = (bf16)v;
        } else {
          Ct[mrow * 128 + col] = (bf16)v;
        }
      }
    }
  }
}

// ---- layer 2: wave per node; out = mean(t[nbr]) + b2l + u[n] ----
__global__ __launch_bounds__(256) void agg2_k(const bf16* __restrict__ tmat,
                                              const bf16* __restrict__ umat,
                                              const int* __restrict__ rowptr,
                                              const int* __restrict__ nbr,
                                              const float* __restrict__ b2l,
                                              float* __restrict__ out, int N) {
  int wave = threadIdx.x >> 6, lane = threadIdx.x & 63;
  int n = blockIdx.x * 4 + wave;
  if (n >= N) return;
  int s = rowptr[n], e = rowptr[n + 1];
  float sum = 0.0f;
  int i = s;
  for (; i + 3 < e; i += 4) {
    int j0 = nbr[i], j1 = nbr[i + 1], j2 = nbr[i + 2], j3 = nbr[i + 3];
    float v0 = (float)tmat[(long)j0 * 64 + lane];
    float v1 = (float)tmat[(long)j1 * 64 + lane];
    float v2 = (float)tmat[(long)j2 * 64 + lane];
    float v3 = (float)tmat[(long)j3 * 64 + lane];
    sum += (v0 + v1) + (v2 + v3);
  }
  for (; i < e; i++) sum += (float)tmat[(long)nbr[i] * 64 + lane];
  out[(long)n * 64 + lane] =
      sum / fmaxf((float)(e - s), 1.0f) + b2l[lane] + (float)umat[(long)n * 64 + lane];
}

static inline size_t align256(size_t x) { return (x + 255) / 256 * 256; }

extern "C" void kernel_launch(void* const* d_in, const int* in_sizes, int n_in,
                              void* d_out, int out_size, void* d_ws, size_t ws_size,
                              hipStream_t stream) {
  const float* x = (const float*)d_in[0];
  const int* edge_index = (const int*)d_in[1];
  const float* W1l = (const float*)d_in[2];
  const float* b1l = (const float*)d_in[3];
  const float* W1r = (const float*)d_in[4];
  const float* W2l = (const float*)d_in[5];
  const float* b2l = (const float*)d_in[6];
  const float* W2r = (const float*)d_in[7];

  const int N = in_sizes[0] / 64;        // 100000
  const int E = in_sizes[1] / 2;         // 1200000
  const int Np = (N + 127) / 128 * 128;  // 100096
  const int nb = Np / 128;               // 782 buckets

  const int* src = edge_index;
  const int* dst = edge_index + E;

  char* ws = (char*)d_ws;
  size_t off = 0;
  int* bcnt = (int*)(ws + off);      off += align256((size_t)nb * 4);
  int* boff = (int*)(ws + off);      off += align256((size_t)(nb + 1) * 4);
  int* bcur = (int*)(ws + off);      off += align256((size_t)nb * 4);
  int* rowptr = (int*)(ws + off);    off += align256((size_t)(Np + 1) * 4);
  uint2* ebuf = (uint2*)(ws + off);  off += align256((size_t)E * 8);
  int* nbr = (int*)(ws + off);       off += align256((size_t)E * 4);
  bf16* xb = (bf16*)(ws + off);      off += align256((size_t)Np * 64 * 2);
  bf16* A1 = (bf16*)(ws + off);      // A1 dead after gemm1 -> reused as t|u
  bf16* tmat = (bf16*)(ws + off);    off += align256((size_t)Np * 64 * 2);
  bf16* umat = (bf16*)(ws + off);    off += align256((size_t)Np * 64 * 2);
  bf16* h = (bf16*)(ws + off);       off += align256((size_t)Np * 128 * 2);
  bf16* B1 = (bf16*)(ws + off);      off += align256(128 * 128 * 2);
  bf16* B2 = (bf16*)(ws + off);      off += align256(128 * 128 * 2);
  float* out = (float*)d_out;

  hipMemsetAsync(bcnt, 0, (size_t)nb * 4, stream);

  build_B_k<<<128, 256, 0, stream>>>(W1l, W1r, W2l, W2r, B1, B2);
  cvt_k<<<(int)(((long)Np * 64 / 4 + 255) / 256), 256, 0, stream>>>(x, xb, N, Np);
  bhist_k<<<256, 256, 0, stream>>>(dst, bcnt, E, nb);
  bscan_k<<<1, 1024, 0, stream>>>(bcnt, boff, bcur, nb, E);
  bfill_k<<<(E + 255) / 256, 256, 0, stream>>>(src, dst, bcur, ebuf, E);
  csr_k<<<nb, 256, 0, stream>>>(ebuf, boff, rowptr, nbr, Np, E);

  agg1_k<<<Np / 4, 256, 0, stream>>>(xb, rowptr, nbr, A1, Np);
  gemm_bf16_k<<<Np / 128, 256, 0, stream>>>(A1, B1, h, nullptr, b1l, 1);
  gemm_bf16_k<<<Np / 128, 256, 0, stream>>>(h, B2, tmat, umat, nullptr, 0);
  agg2_k<<<(N + 3) / 4, 256, 0, stream>>>(tmat, umat, rowptr, nbr, b2l, out, N);
}

// Round 5
// 337.293 us; speedup vs baseline: 4.4225x; 1.7689x over previous
//
#include <hip/hip_runtime.h>
#include <hip/hip_bf16.h>

typedef __bf16 bf16;
typedef __attribute__((ext_vector_type(8))) __bf16 bf16x8;
typedef __attribute__((ext_vector_type(4))) float f32x4;

#define NBLK 128  // radix chunks; per-bucket-per-block run ~12 records

// Pack B1 = [W1l | W1r] as [128 cols][128 k] bf16 (K-major, i.e. B^T form),
//      B2 = [W2l ; W2r] as [128 cols][128 k] bf16.
__global__ __launch_bounds__(256) void build_B_k(const float* __restrict__ W1l,
                                                 const float* __restrict__ W1r,
                                                 const float* __restrict__ W2l,
                                                 const float* __restrict__ W2r,
                                                 bf16* __restrict__ B1,
                                                 bf16* __restrict__ B2) {
  int gid = blockIdx.x * 256 + threadIdx.x;  // 0..32767
  if (gid < 16384) {
    int c = gid >> 7, k = gid & 127;
    float v = (k < 64) ? W1l[c * 64 + k] : W1r[c * 64 + (k - 64)];
    B1[gid] = (bf16)v;
  } else {
    int idx = gid - 16384;
    int n = idx >> 7, k = idx & 127;
    float v = (n < 64) ? W2l[n * 128 + k] : W2r[(n - 64) * 128 + k];
    B2[idx] = (bf16)v;
  }
}

// x (N x 64 f32) -> xb (Np x 64 bf16), zero-padded rows N..Np
__global__ __launch_bounds__(256) void cvt_k(const float* __restrict__ x,
                                             bf16* __restrict__ xb, int N, int Np) {
  int gid = blockIdx.x * 256 + threadIdx.x;  // one per 4 elems
  long base = (long)gid * 4;
  if (base >= (long)Np * 64) return;
  if (base < (long)N * 64) {
    f32x4 v = *(const f32x4*)(x + base);
    bf16 o[4] = {(bf16)v.x, (bf16)v.y, (bf16)v.z, (bf16)v.w};
    *(ulong1*)(xb + base) = *(ulong1*)o;
  } else {
    bf16 o[4] = {(bf16)0.0f, (bf16)0.0f, (bf16)0.0f, (bf16)0.0f};
    *(ulong1*)(xb + base) = *(ulong1*)o;
  }
}

// ---- deterministic 2-pass radix bucket sort by dst>>7 (zero global atomics) ----

// Pass 1: per-chunk LDS histogram -> hist[bucket * NBLK + chunk]
__global__ __launch_bounds__(256) void hist_k(const int* __restrict__ dst,
                                              int* __restrict__ hist, int E, int nb) {
  __shared__ int h[1024];
  for (int i = threadIdx.x; i < nb; i += 256) h[i] = 0;
  __syncthreads();
  int chunk = (E + NBLK - 1) / NBLK;
  int s = blockIdx.x * chunk, e = min(E, s + chunk);
  for (int i = s + threadIdx.x; i < e; i += 256) atomicAdd(&h[dst[i] >> 7], 1);
  __syncthreads();
  for (int i = threadIdx.x; i < nb; i += 256)
    hist[(long)i * NBLK + blockIdx.x] = h[i];
}

// Flat exclusive scan of hist[M], M = nb*NBLK (3 tiny kernels)
__global__ __launch_bounds__(256) void scanA_k(const int* __restrict__ hist,
                                               int* __restrict__ partial,
                                               int* __restrict__ bsum, int M) {
  __shared__ int sd[256];
  int t = threadIdx.x;
  int idx = blockIdx.x * 256 + t;
  int v = (idx < M) ? hist[idx] : 0;
  sd[t] = v;
  __syncthreads();
#pragma unroll
  for (int off = 1; off < 256; off <<= 1) {
    int tv = (t >= off) ? sd[t - off] : 0;
    __syncthreads();
    if (t >= off) sd[t] += tv;
    __syncthreads();
  }
  if (idx < M) partial[idx] = sd[t] - v;
  if (t == 255) bsum[blockIdx.x] = sd[255];
}

__global__ __launch_bounds__(512) void scanB_k(const int* __restrict__ bsum,
                                               int* __restrict__ bsumo, int NB2) {
  __shared__ int sd[512];
  int t = threadIdx.x;
  int v = (t < NB2) ? bsum[t] : 0;
  sd[t] = v;
  __syncthreads();
#pragma unroll
  for (int off = 1; off < 512; off <<= 1) {
    int tv = (t >= off) ? sd[t - off] : 0;
    __syncthreads();
    if (t >= off) sd[t] += tv;
    __syncthreads();
  }
  if (t < NB2) bsumo[t] = sd[t] - v;
}

__global__ __launch_bounds__(256) void scanC_k(const int* __restrict__ partial,
                                               const int* __restrict__ bsumo,
                                               int* __restrict__ shist,
                                               int* __restrict__ boff,
                                               int M, int nb, int E) {
  int idx = blockIdx.x * 256 + threadIdx.x;
  if (idx >= M) return;
  int v = partial[idx] + bsumo[idx >> 8];
  shist[idx] = v;
  if ((idx & (NBLK - 1)) == 0) boff[idx / NBLK] = v;
  if (idx == 0) boff[nb] = E;
}

// Pass 2: re-read chunk, LDS cursors from shist, write (src, local-dst) records.
__global__ __launch_bounds__(256) void scat_k(const int* __restrict__ src,
                                              const int* __restrict__ dst,
                                              const int* __restrict__ shist,
                                              uint2* __restrict__ ebuf, int E, int nb) {
  __shared__ int cur[1024];
  for (int i = threadIdx.x; i < nb; i += 256)
    cur[i] = shist[(long)i * NBLK + blockIdx.x];
  __syncthreads();
  int chunk = (E + NBLK - 1) / NBLK;
  int s = blockIdx.x * chunk, e = min(E, s + chunk);
  for (int i = s + threadIdx.x; i < e; i += 256) {
    int d = dst[i];
    int pos = atomicAdd(&cur[d >> 7], 1);
    ebuf[pos] = make_uint2((unsigned)src[i], (unsigned)(d & 127));
  }
}

// per-bucket LDS counting sort -> node-ordered nbr + rowptr.
__global__ __launch_bounds__(256) void csr_k(const uint2* __restrict__ ebuf,
                                             const int* __restrict__ boff,
                                             int* __restrict__ rowptr,
                                             int* __restrict__ nbr, int Np, int E) {
  __shared__ int hcnt[128];
  __shared__ int hoff[128];
  int b = blockIdx.x, t = threadIdx.x;
  int s = boff[b], e = boff[b + 1];
  if (t < 128) hcnt[t] = 0;
  __syncthreads();
  for (int i = s + t; i < e; i += 256) atomicAdd(&hcnt[ebuf[i].y], 1);
  __syncthreads();
  if (t < 128) hoff[t] = hcnt[t];
  __syncthreads();
#pragma unroll
  for (int off = 1; off < 128; off <<= 1) {
    int v = (t < 128 && t >= off) ? hoff[t - off] : 0;
    __syncthreads();
    if (t < 128 && t >= off) hoff[t] += v;
    __syncthreads();
  }
  if (t < 128) {
    int ex = hoff[t] - hcnt[t];  // exclusive scan
    rowptr[b * 128 + t] = s + ex;
    hcnt[t] = ex;  // becomes relative cursor
  }
  if (blockIdx.x == gridDim.x - 1 && t == 0) rowptr[Np] = E;
  __syncthreads();
  for (int i = s + t; i < e; i += 256) {
    uint2 r = ebuf[i];
    int pos = atomicAdd(&hcnt[r.y], 1);
    nbr[s + pos] = (int)r.x;
  }
}

// ---- layer 1: wave per node, bf16 gathers; A1[n] = [mean(xb[nbr]) | xb[n]] ----
__global__ __launch_bounds__(256) void agg1_k(const bf16* __restrict__ xb,
                                              const int* __restrict__ rowptr,
                                              const int* __restrict__ nbr,
                                              bf16* __restrict__ A1, int Np) {
  int wave = threadIdx.x >> 6, lane = threadIdx.x & 63;
  int n = blockIdx.x * 4 + wave;
  if (n >= Np) return;
  int s = rowptr[n], e = rowptr[n + 1];
  float sum = 0.0f;
  int i = s;
  for (; i + 3 < e; i += 4) {
    int j0 = nbr[i], j1 = nbr[i + 1], j2 = nbr[i + 2], j3 = nbr[i + 3];
    float v0 = (float)xb[(long)j0 * 64 + lane];
    float v1 = (float)xb[(long)j1 * 64 + lane];
    float v2 = (float)xb[(long)j2 * 64 + lane];
    float v3 = (float)xb[(long)j3 * 64 + lane];
    sum += (v0 + v1) + (v2 + v3);
  }
  for (; i < e; i++) sum += (float)xb[(long)nbr[i] * 64 + lane];
  float mean = sum / fmaxf((float)(e - s), 1.0f);
  A1[(long)n * 128 + lane] = (bf16)mean;
  A1[(long)n * 128 + 64 + lane] = xb[(long)n * 64 + lane];  // pads: xb==0
}

// C[Mp x 128] = A[Mp x 128] * B^T, B stored [128 cols][128 k] bf16.
// If Cu != null: cols 0..63 -> Ct (ld 64), cols 64..127 -> Cu (ld 64).
__global__ __launch_bounds__(256) void gemm_bf16_k(const bf16* __restrict__ A,
                                                   const bf16* __restrict__ B,
                                                   bf16* __restrict__ Ct,
                                                   bf16* __restrict__ Cu,
                                                   const float* __restrict__ bias,
                                                   int relu) {
  int wave = threadIdx.x >> 6;
  int lane = threadIdx.x & 63;
  int row = lane & 15;
  int quad = lane >> 4;
  long mbase = (long)blockIdx.x * 128 + (long)wave * 32;

  bf16x8 bfrag[8][4];
#pragma unroll
  for (int j = 0; j < 8; j++)
#pragma unroll
    for (int s = 0; s < 4; s++)
      bfrag[j][s] = *(const bf16x8*)(B + (long)(j * 16 + row) * 128 + s * 32 + quad * 8);

  f32x4 acc[2][8] = {};
#pragma unroll
  for (int s = 0; s < 4; s++) {
    bf16x8 a0 = *(const bf16x8*)(A + (mbase + row) * 128 + s * 32 + quad * 8);
    bf16x8 a1 = *(const bf16x8*)(A + (mbase + 16 + row) * 128 + s * 32 + quad * 8);
#pragma unroll
    for (int j = 0; j < 8; j++) {
      acc[0][j] = __builtin_amdgcn_mfma_f32_16x16x32_bf16(a0, bfrag[j][s], acc[0][j], 0, 0, 0);
      acc[1][j] = __builtin_amdgcn_mfma_f32_16x16x32_bf16(a1, bfrag[j][s], acc[1][j], 0, 0, 0);
    }
  }

#pragma unroll
  for (int r = 0; r < 2; r++) {
    long rb = mbase + r * 16;
#pragma unroll
    for (int j = 0; j < 8; j++) {
      int col = j * 16 + row;
      float bv = bias ? bias[col] : 0.0f;
#pragma unroll
      for (int i = 0; i < 4; i++) {
        float v = acc[r][j][i] + bv;
        if (relu) v = v > 0.0f ? v : 0.0f;
        long mrow = rb + quad * 4 + i;
        if (Cu) {
          if (col < 64) Ct[mrow * 64 + col] = (bf16)v;
          else Cu[mrow * 64 + (col - 64)] = (bf16)v;
        } else {
          Ct[mrow * 128 + col] = (bf16)v;
        }
      }
    }
  }
}

// ---- layer 2: wave per node; out = mean(t[nbr]) + b2l + u[n] ----
__global__ __launch_bounds__(256) void agg2_k(const bf16* __restrict__ tmat,
                                              const bf16* __restrict__ umat,
                                              const int* __restrict__ rowptr,
                                              const int* __restrict__ nbr,
                                              const float* __restrict__ b2l,
                                              float* __restrict__ out, int N) {
  int wave = threadIdx.x >> 6, lane = threadIdx.x & 63;
  int n = blockIdx.x * 4 + wave;
  if (n >= N) return;
  int s = rowptr[n], e = rowptr[n + 1];
  float sum = 0.0f;
  int i = s;
  for (; i + 3 < e; i += 4) {
    int j0 = nbr[i], j1 = nbr[i + 1], j2 = nbr[i + 2], j3 = nbr[i + 3];
    float v0 = (float)tmat[(long)j0 * 64 + lane];
    float v1 = (float)tmat[(long)j1 * 64 + lane];
    float v2 = (float)tmat[(long)j2 * 64 + lane];
    float v3 = (float)tmat[(long)j3 * 64 + lane];
    sum += (v0 + v1) + (v2 + v3);
  }
  for (; i < e; i++) sum += (float)tmat[(long)nbr[i] * 64 + lane];
  out[(long)n * 64 + lane] =
      sum / fmaxf((float)(e - s), 1.0f) + b2l[lane] + (float)umat[(long)n * 64 + lane];
}

static inline size_t align256(size_t x) { return (x + 255) / 256 * 256; }

extern "C" void kernel_launch(void* const* d_in, const int* in_sizes, int n_in,
                              void* d_out, int out_size, void* d_ws, size_t ws_size,
                              hipStream_t stream) {
  const float* x = (const float*)d_in[0];
  const int* edge_index = (const int*)d_in[1];
  const float* W1l = (const float*)d_in[2];
  const float* b1l = (const float*)d_in[3];
  const float* W1r = (const float*)d_in[4];
  const float* W2l = (const float*)d_in[5];
  const float* b2l = (const float*)d_in[6];
  const float* W2r = (const float*)d_in[7];

  const int N = in_sizes[0] / 64;        // 100000
  const int E = in_sizes[1] / 2;         // 1200000
  const int Np = (N + 127) / 128 * 128;  // 100096
  const int nb = Np / 128;               // 782 buckets
  const int M = nb * NBLK;               // hist elements (100096)
  const int NB2 = (M + 255) / 256;       // scanA blocks

  const int* src = edge_index;
  const int* dst = edge_index + E;

  char* ws = (char*)d_ws;
  size_t off = 0;
  int* hist = (int*)(ws + off);      off += align256((size_t)M * 4);
  int* partial = (int*)(ws + off);   off += align256((size_t)M * 4);
  int* shist = (int*)(ws + off);     off += align256((size_t)M * 4);
  int* bsum = (int*)(ws + off);      off += align256((size_t)NB2 * 4);
  int* bsumo = (int*)(ws + off);     off += align256((size_t)NB2 * 4);
  int* boff = (int*)(ws + off);      off += align256((size_t)(nb + 1) * 4);
  int* rowptr = (int*)(ws + off);    off += align256((size_t)(Np + 1) * 4);
  uint2* ebuf = (uint2*)(ws + off);  off += align256((size_t)E * 8);
  int* nbr = (int*)(ws + off);       off += align256((size_t)E * 4);
  bf16* xb = (bf16*)(ws + off);      off += align256((size_t)Np * 64 * 2);
  bf16* A1 = (bf16*)(ws + off);      // A1 dead after gemm1 -> reused as t|u
  bf16* tmat = (bf16*)(ws + off);    off += align256((size_t)Np * 64 * 2);
  bf16* umat = (bf16*)(ws + off);    off += align256((size_t)Np * 64 * 2);
  bf16* h = (bf16*)(ws + off);       off += align256((size_t)Np * 128 * 2);
  bf16* B1 = (bf16*)(ws + off);      off += align256(128 * 128 * 2);
  bf16* B2 = (bf16*)(ws + off);      off += align256(128 * 128 * 2);
  float* out = (float*)d_out;

  build_B_k<<<128, 256, 0, stream>>>(W1l, W1r, W2l, W2r, B1, B2);
  cvt_k<<<(int)(((long)Np * 64 / 4 + 255) / 256), 256, 0, stream>>>(x, xb, N, Np);

  hist_k<<<NBLK, 256, 0, stream>>>(dst, hist, E, nb);
  scanA_k<<<NB2, 256, 0, stream>>>(hist, partial, bsum, M);
  scanB_k<<<1, 512, 0, stream>>>(bsum, bsumo, NB2);
  scanC_k<<<NB2, 256, 0, stream>>>(partial, bsumo, shist, boff, M, nb, E);
  scat_k<<<NBLK, 256, 0, stream>>>(src, dst, shist, ebuf, E, nb);
  csr_k<<<nb, 256, 0, stream>>>(ebuf, boff, rowptr, nbr, Np, E);

  agg1_k<<<Np / 4, 256, 0, stream>>>(xb, rowptr, nbr, A1, Np);
  gemm_bf16_k<<<Np / 128, 256, 0, stream>>>(A1, B1, h, nullptr, b1l, 1);
  gemm_bf16_k<<<Np / 128, 256, 0, stream>>>(h, B2, tmat, umat, nullptr, 0);
  agg2_k<<<(N + 3) / 4, 256, 0, stream>>>(tmat, umat, rowptr, nbr, b2l, out, N);
}

// Round 6
// 287.766 us; speedup vs baseline: 5.1836x; 1.1721x over previous
//
#include <hip/hip_runtime.h>
#include <hip/hip_bf16.h>

typedef __bf16 bf16;
typedef __attribute__((ext_vector_type(8))) __bf16 bf16x8;
typedef __attribute__((ext_vector_type(4))) __bf16 bf16x4;
typedef __attribute__((ext_vector_type(4))) float f32x4;

#define NBLK 128  // radix chunks

// unpack 4 packed bf16 (uint2) -> 4 floats
__device__ inline f32x4 unpack4(uint2 r) {
  f32x4 v;
  v.x = __uint_as_float(r.x << 16);
  v.y = __uint_as_float(r.x & 0xffff0000u);
  v.z = __uint_as_float(r.y << 16);
  v.w = __uint_as_float(r.y & 0xffff0000u);
  return v;
}

// Fused setup: blocks [0,NBLK) histogram; [NBLK,NBLK+128) pack B1/B2; rest cvt x->xb.
__global__ __launch_bounds__(256) void setup_k(const float* __restrict__ x,
                                               const int* __restrict__ dst,
                                               const float* __restrict__ W1l,
                                               const float* __restrict__ W1r,
                                               const float* __restrict__ W2l,
                                               const float* __restrict__ W2r,
                                               bf16* __restrict__ xb,
                                               bf16* __restrict__ B1,
                                               bf16* __restrict__ B2,
                                               int* __restrict__ hist,
                                               int E, int nb, int N, int Np) {
  __shared__ int h[1024];
  int t = threadIdx.x;
  if (blockIdx.x < NBLK) {
    // per-chunk LDS histogram -> hist[bucket * NBLK + chunk]
    for (int i = t; i < nb; i += 256) h[i] = 0;
    __syncthreads();
    int chunk = (E + NBLK - 1) / NBLK;
    int s = blockIdx.x * chunk, e = min(E, s + chunk);
    for (int i = s + t; i < e; i += 256) atomicAdd(&h[dst[i] >> 7], 1);
    __syncthreads();
    for (int i = t; i < nb; i += 256) hist[(long)i * NBLK + blockIdx.x] = h[i];
  } else if (blockIdx.x < NBLK + 128) {
    int gid = (blockIdx.x - NBLK) * 256 + t;  // 0..32767
    if (gid < 16384) {
      int c = gid >> 7, k = gid & 127;
      float v = (k < 64) ? W1l[c * 64 + k] : W1r[c * 64 + (k - 64)];
      B1[gid] = (bf16)v;
    } else {
      int idx = gid - 16384;
      int n = idx >> 7, k = idx & 127;
      float v = (n < 64) ? W2l[n * 128 + k] : W2r[(n - 64) * 128 + k];
      B2[idx] = (bf16)v;
    }
  } else {
    int gid = (blockIdx.x - NBLK - 128) * 256 + t;  // one per 4 elems
    long base = (long)gid * 4;
    if (base >= (long)Np * 64) return;
    if (base < (long)N * 64) {
      f32x4 v = *(const f32x4*)(x + base);
      bf16 o[4] = {(bf16)v.x, (bf16)v.y, (bf16)v.z, (bf16)v.w};
      *(ulong1*)(xb + base) = *(ulong1*)o;
    } else {
      bf16 o[4] = {(bf16)0.0f, (bf16)0.0f, (bf16)0.0f, (bf16)0.0f};
      *(ulong1*)(xb + base) = *(ulong1*)o;
    }
  }
}

// Flat exclusive scan of hist[M], M = nb*NBLK
__global__ __launch_bounds__(256) void scanA_k(const int* __restrict__ hist,
                                               int* __restrict__ partial,
                                               int* __restrict__ bsum, int M) {
  __shared__ int sd[256];
  int t = threadIdx.x;
  int idx = blockIdx.x * 256 + t;
  int v = (idx < M) ? hist[idx] : 0;
  sd[t] = v;
  __syncthreads();
#pragma unroll
  for (int off = 1; off < 256; off <<= 1) {
    int tv = (t >= off) ? sd[t - off] : 0;
    __syncthreads();
    if (t >= off) sd[t] += tv;
    __syncthreads();
  }
  if (idx < M) partial[idx] = sd[t] - v;
  if (t == 255) bsum[blockIdx.x] = sd[255];
}

__global__ __launch_bounds__(512) void scanB_k(const int* __restrict__ bsum,
                                               int* __restrict__ bsumo, int NB2) {
  __shared__ int sd[512];
  int t = threadIdx.x;
  int v = (t < NB2) ? bsum[t] : 0;
  sd[t] = v;
  __syncthreads();
#pragma unroll
  for (int off = 1; off < 512; off <<= 1) {
    int tv = (t >= off) ? sd[t - off] : 0;
    __syncthreads();
    if (t >= off) sd[t] += tv;
    __syncthreads();
  }
  if (t < NB2) bsumo[t] = sd[t] - v;
}

__global__ __launch_bounds__(256) void scanC_k(const int* __restrict__ partial,
                                               const int* __restrict__ bsumo,
                                               int* __restrict__ shist,
                                               int* __restrict__ boff,
                                               int M, int nb, int E) {
  int idx = blockIdx.x * 256 + threadIdx.x;
  if (idx >= M) return;
  int v = partial[idx] + bsumo[idx >> 8];
  shist[idx] = v;
  if ((idx & (NBLK - 1)) == 0) boff[idx / NBLK] = v;
  if (idx == 0) boff[nb] = E;
}

// Pass 2: re-read chunk, LDS cursors from shist, write (src, local-dst) records.
__global__ __launch_bounds__(256) void scat_k(const int* __restrict__ src,
                                              const int* __restrict__ dst,
                                              const int* __restrict__ shist,
                                              uint2* __restrict__ ebuf, int E, int nb) {
  __shared__ int cur[1024];
  for (int i = threadIdx.x; i < nb; i += 256)
    cur[i] = shist[(long)i * NBLK + blockIdx.x];
  __syncthreads();
  int chunk = (E + NBLK - 1) / NBLK;
  int s = blockIdx.x * chunk, e = min(E, s + chunk);
  for (int i = s + threadIdx.x; i < e; i += 256) {
    int d = dst[i];
    int pos = atomicAdd(&cur[d >> 7], 1);
    ebuf[pos] = make_uint2((unsigned)src[i], (unsigned)(d & 127));
  }
}

// per-bucket LDS counting sort -> node-ordered nbr + rowptr.
__global__ __launch_bounds__(256) void csr_k(const uint2* __restrict__ ebuf,
                                             const int* __restrict__ boff,
                                             int* __restrict__ rowptr,
                                             int* __restrict__ nbr, int Np, int E) {
  __shared__ int hcnt[128];
  __shared__ int hoff[128];
  int b = blockIdx.x, t = threadIdx.x;
  int s = boff[b], e = boff[b + 1];
  if (t < 128) hcnt[t] = 0;
  __syncthreads();
  for (int i = s + t; i < e; i += 256) atomicAdd(&hcnt[ebuf[i].y], 1);
  __syncthreads();
  if (t < 128) hoff[t] = hcnt[t];
  __syncthreads();
#pragma unroll
  for (int off = 1; off < 128; off <<= 1) {
    int v = (t < 128 && t >= off) ? hoff[t - off] : 0;
    __syncthreads();
    if (t < 128 && t >= off) hoff[t] += v;
    __syncthreads();
  }
  if (t < 128) {
    int ex = hoff[t] - hcnt[t];  // exclusive scan
    rowptr[b * 128 + t] = s + ex;
    hcnt[t] = ex;  // becomes relative cursor
  }
  if (blockIdx.x == gridDim.x - 1 && t == 0) rowptr[Np] = E;
  __syncthreads();
  for (int i = s + t; i < e; i += 256) {
    uint2 r = ebuf[i];
    int pos = atomicAdd(&hcnt[r.y], 1);
    nbr[s + pos] = (int)r.x;
  }
}

// ---- layer 1: wave per node, 4 rows per wave-load ----
// quarter q = lane>>4 owns edge slot q; 16 lanes cover a 128 B row (uint2 each).
__global__ __launch_bounds__(256) void agg1_k(const bf16* __restrict__ xb,
                                              const int* __restrict__ rowptr,
                                              const int* __restrict__ nbr,
                                              bf16* __restrict__ A1, int Np) {
  int wave = threadIdx.x >> 6, lane = threadIdx.x & 63;
  int n = blockIdx.x * 4 + wave;
  if (n >= Np) return;
  int s = rowptr[n], e = rowptr[n + 1];
  int q = lane >> 4, f = lane & 15;
  int fo = f * 4;  // feature base (4 feats per lane)
  f32x4 sum = {0.0f, 0.0f, 0.0f, 0.0f};
  int i = s;
  for (; i + 7 < e; i += 8) {
    int jA = nbr[i + q];
    int jB = nbr[i + 4 + q];
    uint2 ra = *(const uint2*)(xb + jA * 64 + fo);
    uint2 rb = *(const uint2*)(xb + jB * 64 + fo);
    sum += unpack4(ra);
    sum += unpack4(rb);
  }
  for (; i < e; i += 4) {
    int idx = i + q;
    bool act = idx < e;
    int j = act ? nbr[idx] : 0;
    uint2 r = act ? *(const uint2*)(xb + j * 64 + fo) : make_uint2(0u, 0u);
    sum += unpack4(r);
  }
  float s0 = sum.x, s1 = sum.y, s2 = sum.z, s3 = sum.w;
  s0 += __shfl_xor(s0, 16); s0 += __shfl_xor(s0, 32);
  s1 += __shfl_xor(s1, 16); s1 += __shfl_xor(s1, 32);
  s2 += __shfl_xor(s2, 16); s2 += __shfl_xor(s2, 32);
  s3 += __shfl_xor(s3, 16); s3 += __shfl_xor(s3, 32);
  float invd = 1.0f / fmaxf((float)(e - s), 1.0f);
  if (q == 0) {
    bf16x4 o = {(bf16)(s0 * invd), (bf16)(s1 * invd), (bf16)(s2 * invd), (bf16)(s3 * invd)};
    *(bf16x4*)(A1 + n * 128 + fo) = o;
  } else if (q == 1) {
    uint2 rv = *(const uint2*)(xb + n * 64 + fo);  // pads: xb==0
    *(uint2*)(A1 + n * 128 + 64 + fo) = rv;
  }
}

// C[Mp x 128] = A[Mp x 128] * B^T, B stored [128 cols][128 k] bf16.
// If Cu != null: cols 0..63 -> Ct (ld 64), cols 64..127 -> Cu (ld 64).
__global__ __launch_bounds__(256) void gemm_bf16_k(const bf16* __restrict__ A,
                                                   const bf16* __restrict__ B,
                                                   bf16* __restrict__ Ct,
                                                   bf16* __restrict__ Cu,
                                                   const float* __restrict__ bias,
                                                   int relu) {
  int wave = threadIdx.x >> 6;
  int lane = threadIdx.x & 63;
  int row = lane & 15;
  int quad = lane >> 4;
  long mbase = (long)blockIdx.x * 128 + (long)wave * 32;

  bf16x8 bfrag[8][4];
#pragma unroll
  for (int j = 0; j < 8; j++)
#pragma unroll
    for (int s = 0; s < 4; s++)
      bfrag[j][s] = *(const bf16x8*)(B + (long)(j * 16 + row) * 128 + s * 32 + quad * 8);

  f32x4 acc[2][8] = {};
#pragma unroll
  for (int s = 0; s < 4; s++) {
    bf16x8 a0 = *(const bf16x8*)(A + (mbase + row) * 128 + s * 32 + quad * 8);
    bf16x8 a1 = *(const bf16x8*)(A + (mbase + 16 + row) * 128 + s * 32 + quad * 8);
#pragma unroll
    for (int j = 0; j < 8; j++) {
      acc[0][j] = __builtin_amdgcn_mfma_f32_16x16x32_bf16(a0, bfrag[j][s], acc[0][j], 0, 0, 0);
      acc[1][j] = __builtin_amdgcn_mfma_f32_16x16x32_bf16(a1, bfrag[j][s], acc[1][j], 0, 0, 0);
    }
  }

#pragma unroll
  for (int r = 0; r < 2; r++) {
    long rb = mbase + r * 16;
#pragma unroll
    for (int j = 0; j < 8; j++) {
      int col = j * 16 + row;
      float bv = bias ? bias[col] : 0.0f;
#pragma unroll
      for (int i = 0; i < 4; i++) {
        float v = acc[r][j][i] + bv;
        if (relu) v = v > 0.0f ? v : 0.0f;
        long mrow = rb + quad * 4 + i;
        if (Cu) {
          if (col < 64) Ct[mrow * 64 + col] = (bf16)v;
          else Cu[mrow * 64 + (col - 64)] = (bf16)v;
        } else {
          Ct[mrow * 128 + col] = (bf16)v;
        }
      }
    }
  }
}

// ---- layer 2: wave per node, 4 rows per wave-load; fused bias + root + out ----
__global__ __launch_bounds__(256) void agg2_k(const bf16* __restrict__ tmat,
                                              const bf16* __restrict__ umat,
                                              const int* __restrict__ rowptr,
                                              const int* __restrict__ nbr,
                                              const float* __restrict__ b2l,
                                              float* __restrict__ out, int N) {
  int wave = threadIdx.x >> 6, lane = threadIdx.x & 63;
  int n = blockIdx.x * 4 + wave;
  if (n >= N) return;
  int s = rowptr[n], e = rowptr[n + 1];
  int q = lane >> 4, f = lane & 15;
  int fo = f * 4;
  f32x4 sum = {0.0f, 0.0f, 0.0f, 0.0f};
  int i = s;
  for (; i + 7 < e; i += 8) {
    int jA = nbr[i + q];
    int jB = nbr[i + 4 + q];
    uint2 ra = *(const uint2*)(tmat + jA * 64 + fo);
    uint2 rb = *(const uint2*)(tmat + jB * 64 + fo);
    sum += unpack4(ra);
    sum += unpack4(rb);
  }
  for (; i < e; i += 4) {
    int idx = i + q;
    bool act = idx < e;
    int j = act ? nbr[idx] : 0;
    uint2 r = act ? *(const uint2*)(tmat + j * 64 + fo) : make_uint2(0u, 0u);
    sum += unpack4(r);
  }
  float s0 = sum.x, s1 = sum.y, s2 = sum.z, s3 = sum.w;
  s0 += __shfl_xor(s0, 16); s0 += __shfl_xor(s0, 32);
  s1 += __shfl_xor(s1, 16); s1 += __shfl_xor(s1, 32);
  s2 += __shfl_xor(s2, 16); s2 += __shfl_xor(s2, 32);
  s3 += __shfl_xor(s3, 16); s3 += __shfl_xor(s3, 32);
  if (q == 0) {
    float invd = 1.0f / fmaxf((float)(e - s), 1.0f);
    f32x4 b = *(const f32x4*)(b2l + fo);
    f32x4 u = unpack4(*(const uint2*)(umat + n * 64 + fo));
    f32x4 o;
    o.x = s0 * invd + b.x + u.x;
    o.y = s1 * invd + b.y + u.y;
    o.z = s2 * invd + b.z + u.z;
    o.w = s3 * invd + b.w + u.w;
    *(f32x4*)(out + n * 64 + fo) = o;
  }
}

static inline size_t align256(size_t x) { return (x + 255) / 256 * 256; }

extern "C" void kernel_launch(void* const* d_in, const int* in_sizes, int n_in,
                              void* d_out, int out_size, void* d_ws, size_t ws_size,
                              hipStream_t stream) {
  const float* x = (const float*)d_in[0];
  const int* edge_index = (const int*)d_in[1];
  const float* W1l = (const float*)d_in[2];
  const float* b1l = (const float*)d_in[3];
  const float* W1r = (const float*)d_in[4];
  const float* W2l = (const float*)d_in[5];
  const float* b2l = (const float*)d_in[6];
  const float* W2r = (const float*)d_in[7];

  const int N = in_sizes[0] / 64;        // 100000
  const int E = in_sizes[1] / 2;         // 1200000
  const int Np = (N + 127) / 128 * 128;  // 100096
  const int nb = Np / 128;               // 782 buckets
  const int M = nb * NBLK;               // hist elements
  const int NB2 = (M + 255) / 256;       // scanA blocks

  const int* src = edge_index;
  const int* dst = edge_index + E;

  char* ws = (char*)d_ws;
  size_t off = 0;
  int* hist = (int*)(ws + off);      off += align256((size_t)M * 4);
  int* partial = (int*)(ws + off);   off += align256((size_t)M * 4);
  int* shist = (int*)(ws + off);     off += align256((size_t)M * 4);
  int* bsum = (int*)(ws + off);      off += align256((size_t)NB2 * 4);
  int* bsumo = (int*)(ws + off);     off += align256((size_t)NB2 * 4);
  int* boff = (int*)(ws + off);      off += align256((size_t)(nb + 1) * 4);
  int* rowptr = (int*)(ws + off);    off += align256((size_t)(Np + 1) * 4);
  uint2* ebuf = (uint2*)(ws + off);  off += align256((size_t)E * 8);
  int* nbr = (int*)(ws + off);       off += align256((size_t)E * 4);
  bf16* xb = (bf16*)(ws + off);      off += align256((size_t)Np * 64 * 2);
  bf16* A1 = (bf16*)(ws + off);      // A1 dead after gemm1 -> reused as t|u
  bf16* tmat = (bf16*)(ws + off);    off += align256((size_t)Np * 64 * 2);
  bf16* umat = (bf16*)(ws + off);    off += align256((size_t)Np * 64 * 2);
  bf16* h = (bf16*)(ws + off);       off += align256((size_t)Np * 128 * 2);
  bf16* B1 = (bf16*)(ws + off);      off += align256(128 * 128 * 2);
  bf16* B2 = (bf16*)(ws + off);      off += align256(128 * 128 * 2);
  float* out = (float*)d_out;

  const int cvtBlocks = (int)(((long)Np * 64 / 4 + 255) / 256);
  setup_k<<<NBLK + 128 + cvtBlocks, 256, 0, stream>>>(x, dst, W1l, W1r, W2l, W2r,
                                                      xb, B1, B2, hist, E, nb, N, Np);
  scanA_k<<<NB2, 256, 0, stream>>>(hist, partial, bsum, M);
  scanB_k<<<1, 512, 0, stream>>>(bsum, bsumo, NB2);
  scanC_k<<<NB2, 256, 0, stream>>>(partial, bsumo, shist, boff, M, nb, E);
  scat_k<<<NBLK, 256, 0, stream>>>(src, dst, shist, ebuf, E, nb);
  csr_k<<<nb, 256, 0, stream>>>(ebuf, boff, rowptr, nbr, Np, E);

  agg1_k<<<Np / 4, 256, 0, stream>>>(xb, rowptr, nbr, A1, Np);
  gemm_bf16_k<<<Np / 128, 256, 0, stream>>>(A1, B1, h, nullptr, b1l, 1);
  gemm_bf16_k<<<Np / 128, 256, 0, stream>>>(h, B2, tmat, umat, nullptr, 0);
  agg2_k<<<(N + 3) / 4, 256, 0, stream>>>(tmat, umat, rowptr, nbr, b2l, out, N);
}

// Round 8
// 263.653 us; speedup vs baseline: 5.6577x; 1.0915x over previous
//
#include <hip/hip_runtime.h>
#include <hip/hip_bf16.h>

typedef __bf16 bf16;
typedef __attribute__((ext_vector_type(8))) __bf16 bf16x8;
typedef __attribute__((ext_vector_type(4))) __bf16 bf16x4;
typedef __attribute__((ext_vector_type(4))) float f32x4;

#define NBLK 256  // radix chunks

// unpack 8 packed bf16 (uint4) -> two f32x4
__device__ inline void unpack8(uint4 r, f32x4& a, f32x4& b) {
  a.x = __uint_as_float(r.x << 16);
  a.y = __uint_as_float(r.x & 0xffff0000u);
  a.z = __uint_as_float(r.y << 16);
  a.w = __uint_as_float(r.y & 0xffff0000u);
  b.x = __uint_as_float(r.z << 16);
  b.y = __uint_as_float(r.z & 0xffff0000u);
  b.z = __uint_as_float(r.w << 16);
  b.w = __uint_as_float(r.w & 0xffff0000u);
}

// predicated 8-rows-per-wave slot load: slot q = lane>>3, 8 lanes cover a 128 B row
__device__ inline uint4 slot_load(const bf16* __restrict__ tab, const int* __restrict__ nbr,
                                  int base, int e, int q, int fo) {
  int idx = base + q;
  uint4 r = make_uint4(0u, 0u, 0u, 0u);
  if (idx < e) {
    int j = nbr[idx];
    r = *(const uint4*)(tab + j * 64 + fo);
  }
  return r;
}

// Fused setup: blocks [0,NBLK) histogram; [NBLK,NBLK+128) pack B1/B2; rest cvt x->xb.
__global__ __launch_bounds__(256) void setup_k(const float* __restrict__ x,
                                               const int* __restrict__ dst,
                                               const float* __restrict__ W1l,
                                               const float* __restrict__ W1r,
                                               const float* __restrict__ W2l,
                                               const float* __restrict__ W2r,
                                               bf16* __restrict__ xb,
                                               bf16* __restrict__ B1,
                                               bf16* __restrict__ B2,
                                               int* __restrict__ hist,
                                               int E, int nb, int N, int Np) {
  __shared__ int h[1024];
  int t = threadIdx.x;
  if (blockIdx.x < NBLK) {
    // per-chunk LDS histogram -> hist[bucket * NBLK + chunk]
    for (int i = t; i < nb; i += 256) h[i] = 0;
    __syncthreads();
    int chunk = (E + NBLK - 1) / NBLK;
    int s = blockIdx.x * chunk, e = min(E, s + chunk);
    for (int i = s + t; i < e; i += 256) atomicAdd(&h[dst[i] >> 7], 1);
    __syncthreads();
    for (int i = t; i < nb; i += 256) hist[(long)i * NBLK + blockIdx.x] = h[i];
  } else if (blockIdx.x < NBLK + 128) {
    int gid = (blockIdx.x - NBLK) * 256 + t;  // 0..32767
    if (gid < 16384) {
      int c = gid >> 7, k = gid & 127;
      float v = (k < 64) ? W1l[c * 64 + k] : W1r[c * 64 + (k - 64)];
      B1[gid] = (bf16)v;
    } else {
      int idx = gid - 16384;
      int n = idx >> 7, k = idx & 127;
      float v = (n < 64) ? W2l[n * 128 + k] : W2r[(n - 64) * 128 + k];
      B2[idx] = (bf16)v;
    }
  } else {
    int gid = (blockIdx.x - NBLK - 128) * 256 + t;  // one per 4 elems
    long base = (long)gid * 4;
    if (base >= (long)Np * 64) return;
    if (base < (long)N * 64) {
      f32x4 v = *(const f32x4*)(x + base);
      bf16 o[4] = {(bf16)v.x, (bf16)v.y, (bf16)v.z, (bf16)v.w};
      *(ulong1*)(xb + base) = *(ulong1*)o;
    } else {
      bf16 o[4] = {(bf16)0.0f, (bf16)0.0f, (bf16)0.0f, (bf16)0.0f};
      *(ulong1*)(xb + base) = *(ulong1*)o;
    }
  }
}

// In-place flat exclusive scan of hist[M], M = nb*NBLK.
// scanA: per-block exclusive scan in place, block total -> bsum.
__global__ __launch_bounds__(256) void scanA_k(int* __restrict__ hist,
                                               int* __restrict__ bsum, int M) {
  __shared__ int sd[256];
  int t = threadIdx.x;
  int idx = blockIdx.x * 256 + t;
  int v = (idx < M) ? hist[idx] : 0;
  sd[t] = v;
  __syncthreads();
#pragma unroll
  for (int off = 1; off < 256; off <<= 1) {
    int tv = (t >= off) ? sd[t - off] : 0;
    __syncthreads();
    if (t >= off) sd[t] += tv;
    __syncthreads();
  }
  if (idx < M) hist[idx] = sd[t] - v;
  if (t == 255) bsum[blockIdx.x] = sd[255];
}

// scanB: single-block in-place exclusive scan of bsum (NB2 <= 1024)
__global__ __launch_bounds__(1024) void scanB_k(int* __restrict__ bsum, int NB2) {
  __shared__ int sd[1024];
  int t = threadIdx.x;
  int v = (t < NB2) ? bsum[t] : 0;
  sd[t] = v;
  __syncthreads();
#pragma unroll
  for (int off = 1; off < 1024; off <<= 1) {
    int tv = (t >= off) ? sd[t - off] : 0;
    __syncthreads();
    if (t >= off) sd[t] += tv;
    __syncthreads();
  }
  if (t < NB2) bsum[t] = sd[t] - v;
}

// scanC: hist[idx] += block offset (global exclusive prefix, in place); bucket bases.
__global__ __launch_bounds__(256) void scanC_k(int* __restrict__ hist,
                                               const int* __restrict__ bsum,
                                               int* __restrict__ boff,
                                               int M, int nb, int E) {
  int idx = blockIdx.x * 256 + threadIdx.x;
  if (idx >= M) return;
  int v = hist[idx] + bsum[idx >> 8];
  hist[idx] = v;
  if ((idx & (NBLK - 1)) == 0) boff[idx / NBLK] = v;
  if (idx == 0) boff[nb] = E;
}

// Pass 2: re-read chunk, LDS cursors from hist (=global prefixes), write packed
// records (src<<7 | local-dst) into bucket regions.
__global__ __launch_bounds__(512) void scat_k(const int* __restrict__ src,
                                              const int* __restrict__ dst,
                                              const int* __restrict__ hist,
                                              unsigned* __restrict__ ebuf, int E, int nb) {
  __shared__ int cur[1024];
  for (int i = threadIdx.x; i < nb; i += 512)
    cur[i] = hist[(long)i * NBLK + blockIdx.x];
  __syncthreads();
  int chunk = (E + NBLK - 1) / NBLK;
  int s = blockIdx.x * chunk, e = min(E, s + chunk);
  for (int i = s + threadIdx.x; i < e; i += 512) {
    int d = dst[i];
    int pos = atomicAdd(&cur[d >> 7], 1);
    ebuf[pos] = ((unsigned)src[i] << 7) | (unsigned)(d & 127);
  }
}

// per-bucket LDS counting sort -> node-ordered nbr + rowptr.
__global__ __launch_bounds__(256) void csr_k(const unsigned* __restrict__ ebuf,
                                             const int* __restrict__ boff,
                                             int* __restrict__ rowptr,
                                             int* __restrict__ nbr, int Np, int E) {
  __shared__ int hcnt[128];
  __shared__ int hoff[128];
  int b = blockIdx.x, t = threadIdx.x;
  int s = boff[b], e = boff[b + 1];
  if (t < 128) hcnt[t] = 0;
  __syncthreads();
  for (int i = s + t; i < e; i += 256) atomicAdd(&hcnt[ebuf[i] & 127u], 1);
  __syncthreads();
  if (t < 128) hoff[t] = hcnt[t];
  __syncthreads();
#pragma unroll
  for (int off = 1; off < 128; off <<= 1) {
    int v = (t < 128 && t >= off) ? hoff[t - off] : 0;
    __syncthreads();
    if (t < 128 && t >= off) hoff[t] += v;
    __syncthreads();
  }
  if (t < 128) {
    int ex = hoff[t] - hcnt[t];  // exclusive scan
    rowptr[b * 128 + t] = s + ex;
    hcnt[t] = ex;  // becomes relative cursor
  }
  if (blockIdx.x == gridDim.x - 1 && t == 0) rowptr[Np] = E;
  __syncthreads();
  for (int i = s + t; i < e; i += 256) {
    unsigned r = ebuf[i];
    int pos = atomicAdd(&hcnt[r & 127u], 1);
    nbr[s + pos] = (int)(r >> 7);
  }
}

// ---- layer 1: wave per node; 8 lanes/row uint4 gathers, depth-2 pipeline ----
__global__ __launch_bounds__(256) void agg1_k(const bf16* __restrict__ xb,
                                              const int* __restrict__ rowptr,
                                              const int* __restrict__ nbr,
                                              bf16* __restrict__ A1, int Np) {
  int wave = threadIdx.x >> 6, lane = threadIdx.x & 63;
  int n = blockIdx.x * 4 + wave;
  if (n >= Np) return;
  int s = rowptr[n], e = rowptr[n + 1];
  int q = lane >> 3, f = lane & 7;
  int fo = f * 8;  // 8 features per lane (16 B)
  f32x4 sa = {0, 0, 0, 0}, sb = {0, 0, 0, 0};
  uint4 c0 = slot_load(xb, nbr, s, e, q, fo);
  uint4 c1 = slot_load(xb, nbr, s + 8, e, q, fo);
  int i = s + 16;
  for (; i < e; i += 16) {
    uint4 n0 = slot_load(xb, nbr, i, e, q, fo);
    uint4 n1 = slot_load(xb, nbr, i + 8, e, q, fo);
    f32x4 a, b;
    unpack8(c0, a, b); sa += a; sb += b;
    unpack8(c1, a, b); sa += a; sb += b;
    c0 = n0; c1 = n1;
  }
  {
    f32x4 a, b;
    unpack8(c0, a, b); sa += a; sb += b;
    unpack8(c1, a, b); sa += a; sb += b;
  }
  float v[8] = {sa.x, sa.y, sa.z, sa.w, sb.x, sb.y, sb.z, sb.w};
#pragma unroll
  for (int k = 0; k < 8; k++) {
    v[k] += __shfl_xor(v[k], 8);
    v[k] += __shfl_xor(v[k], 16);
    v[k] += __shfl_xor(v[k], 32);
  }
  float invd = 1.0f / fmaxf((float)(e - s), 1.0f);
  if (q == 0) {
    bf16x8 o = {(bf16)(v[0] * invd), (bf16)(v[1] * invd), (bf16)(v[2] * invd),
                (bf16)(v[3] * invd), (bf16)(v[4] * invd), (bf16)(v[5] * invd),
                (bf16)(v[6] * invd), (bf16)(v[7] * invd)};
    *(bf16x8*)(A1 + n * 128 + fo) = o;
  } else if (q == 1) {
    uint4 rv = *(const uint4*)(xb + n * 64 + fo);  // pads: xb==0
    *(uint4*)(A1 + n * 128 + 64 + fo) = rv;
  }
}

// C[Mp x 128] = A[Mp x 128] * B^T, B stored [128 cols][128 k] bf16.
// If Cu != null: cols 0..63 -> Ct (ld 64), cols 64..127 -> Cu (ld 64).
__global__ __launch_bounds__(256) void gemm_bf16_k(const bf16* __restrict__ A,
                                                   const bf16* __restrict__ B,
                                                   bf16* __restrict__ Ct,
                                                   bf16* __restrict__ Cu,
                                                   const float* __restrict__ bias,
                                                   int relu) {
  int wave = threadIdx.x >> 6;
  int lane = threadIdx.x & 63;
  int row = lane & 15;
  int quad = lane >> 4;
  long mbase = (long)blockIdx.x * 128 + (long)wave * 32;

  bf16x8 bfrag[8][4];
#pragma unroll
  for (int j = 0; j < 8; j++)
#pragma unroll
    for (int s = 0; s < 4; s++)
      bfrag[j][s] = *(const bf16x8*)(B + (long)(j * 16 + row) * 128 + s * 32 + quad * 8);

  f32x4 acc[2][8] = {};
#pragma unroll
  for (int s = 0; s < 4; s++) {
    bf16x8 a0 = *(const bf16x8*)(A + (mbase + row) * 128 + s * 32 + quad * 8);
    bf16x8 a1 = *(const bf16x8*)(A + (mbase + 16 + row) * 128 + s * 32 + quad * 8);
#pragma unroll
    for (int j = 0; j < 8; j++) {
      acc[0][j] = __builtin_amdgcn_mfma_f32_16x16x32_bf16(a0, bfrag[j][s], acc[0][j], 0, 0, 0);
      acc[1][j] = __builtin_amdgcn_mfma_f32_16x16x32_bf16(a1, bfrag[j][s], acc[1][j], 0, 0, 0);
    }
  }

#pragma unroll
  for (int r = 0; r < 2; r++) {
    long rb = mbase + r * 16;
#pragma unroll
    for (int j = 0; j < 8; j++) {
      int col = j * 16 + row;
      float bv = bias ? bias[col] : 0.0f;
#pragma unroll
      for (int i = 0; i < 4; i++) {
        float v = acc[r][j][i] + bv;
        if (relu) v = v > 0.0f ? v : 0.0f;
        long mrow = rb + quad * 4 + i;
        if (Cu) {
          if (col < 64) Ct[mrow * 64 + col] = (bf16)v;
          else Cu[mrow * 64 + (col - 64)] = (bf16)v;
        } else {
          Ct[mrow * 128 + col] = (bf16)v;
        }
      }
    }
  }
}

// ---- layer 2: wave per node; 8 lanes/row uint4 gathers; fused bias+root+out ----
__global__ __launch_bounds__(256) void agg2_k(const bf16* __restrict__ tmat,
                                              const bf16* __restrict__ umat,
                                              const int* __restrict__ rowptr,
                                              const int* __restrict__ nbr,
                                              const float* __restrict__ b2l,
                                              float* __restrict__ out, int N) {
  int wave = threadIdx.x >> 6, lane = threadIdx.x & 63;
  int n = blockIdx.x * 4 + wave;
  if (n >= N) return;
  int s = rowptr[n], e = rowptr[n + 1];
  int q = lane >> 3, f = lane & 7;
  int fo = f * 8;
  f32x4 sa = {0, 0, 0, 0}, sb = {0, 0, 0, 0};
  uint4 c0 = slot_load(tmat, nbr, s, e, q, fo);
  uint4 c1 = slot_load(tmat, nbr, s + 8, e, q, fo);
  int i = s + 16;
  for (; i < e; i += 16) {
    uint4 n0 = slot_load(tmat, nbr, i, e, q, fo);
    uint4 n1 = slot_load(tmat, nbr, i + 8, e, q, fo);
    f32x4 a, b;
    unpack8(c0, a, b); sa += a; sb += b;
    unpack8(c1, a, b); sa += a; sb += b;
    c0 = n0; c1 = n1;
  }
  {
    f32x4 a, b;
    unpack8(c0, a, b); sa += a; sb += b;
    unpack8(c1, a, b); sa += a; sb += b;
  }
  float v[8] = {sa.x, sa.y, sa.z, sa.w, sb.x, sb.y, sb.z, sb.w};
#pragma unroll
  for (int k = 0; k < 8; k++) {
    v[k] += __shfl_xor(v[k], 8);
    v[k] += __shfl_xor(v[k], 16);
    v[k] += __shfl_xor(v[k], 32);
  }
  if (q == 0) {
    float invd = 1.0f / fmaxf((float)(e - s), 1.0f);
    f32x4 b0 = *(const f32x4*)(b2l + fo);
    f32x4 b1 = *(const f32x4*)(b2l + fo + 4);
    f32x4 ua, ub;
    unpack8(*(const uint4*)(umat + n * 64 + fo), ua, ub);
    f32x4 o0, o1;
    o0.x = v[0] * invd + b0.x + ua.x;
    o0.y = v[1] * invd + b0.y + ua.y;
    o0.z = v[2] * invd + b0.z + ua.z;
    o0.w = v[3] * invd + b0.w + ua.w;
    o1.x = v[4] * invd + b1.x + ub.x;
    o1.y = v[5] * invd + b1.y + ub.y;
    o1.z = v[6] * invd + b1.z + ub.z;
    o1.w = v[7] * invd + b1.w + ub.w;
    *(f32x4*)(out + n * 64 + fo) = o0;
    *(f32x4*)(out + n * 64 + fo + 4) = o1;
  }
}

static inline size_t align256(size_t x) { return (x + 255) / 256 * 256; }

extern "C" void kernel_launch(void* const* d_in, const int* in_sizes, int n_in,
                              void* d_out, int out_size, void* d_ws, size_t ws_size,
                              hipStream_t stream) {
  const float* x = (const float*)d_in[0];
  const int* edge_index = (const int*)d_in[1];
  const float* W1l = (const float*)d_in[2];
  const float* b1l = (const float*)d_in[3];
  const float* W1r = (const float*)d_in[4];
  const float* W2l = (const float*)d_in[5];
  const float* b2l = (const float*)d_in[6];
  const float* W2r = (const float*)d_in[7];

  const int N = in_sizes[0] / 64;        // 100000
  const int E = in_sizes[1] / 2;         // 1200000
  const int Np = (N + 127) / 128 * 128;  // 100096
  const int nb = Np / 128;               // 782 buckets
  const int M = nb * NBLK;               // hist elements (200192)
  const int NB2 = (M + 255) / 256;       // scanA blocks (<=1024 for scanB)

  const int* src = edge_index;
  const int* dst = edge_index + E;

  // ws layout (~76 MB; R6's proven-safe usage was ~80 MB — stay below it)
  char* ws = (char*)d_ws;
  size_t off = 0;
  int* hist = (int*)(ws + off);         off += align256((size_t)M * 4);
  int* bsum = (int*)(ws + off);         off += align256((size_t)NB2 * 4);
  int* boff = (int*)(ws + off);         off += align256((size_t)(nb + 1) * 4);
  int* rowptr = (int*)(ws + off);       off += align256((size_t)(Np + 1) * 4);
  unsigned* ebuf = (unsigned*)(ws + off); off += align256((size_t)E * 4);
  int* nbr = (int*)(ws + off);          off += align256((size_t)E * 4);
  bf16* xb = (bf16*)(ws + off);         off += align256((size_t)Np * 64 * 2);
  bf16* A1 = (bf16*)(ws + off);         // A1 dead after gemm1 -> reused as t|u
  bf16* tmat = (bf16*)(ws + off);       off += align256((size_t)Np * 64 * 2);
  bf16* umat = (bf16*)(ws + off);       off += align256((size_t)Np * 64 * 2);
  bf16* h = (bf16*)(ws + off);          off += align256((size_t)Np * 128 * 2);
  bf16* B1 = (bf16*)(ws + off);         off += align256(128 * 128 * 2);
  bf16* B2 = (bf16*)(ws + off);         off += align256(128 * 128 * 2);
  float* out = (float*)d_out;

  const int cvtBlocks = (int)(((long)Np * 64 / 4 + 255) / 256);
  setup_k<<<NBLK + 128 + cvtBlocks, 256, 0, stream>>>(x, dst, W1l, W1r, W2l, W2r,
                                                      xb, B1, B2, hist, E, nb, N, Np);
  scanA_k<<<NB2, 256, 0, stream>>>(hist, bsum, M);
  scanB_k<<<1, 1024, 0, stream>>>(bsum, NB2);
  scanC_k<<<(M + 255) / 256, 256, 0, stream>>>(hist, bsum, boff, M, nb, E);
  scat_k<<<NBLK, 512, 0, stream>>>(src, dst, hist, ebuf, E, nb);
  csr_k<<<nb, 256, 0, stream>>>(ebuf, boff, rowptr, nbr, Np, E);

  agg1_k<<<Np / 4, 256, 0, stream>>>(xb, rowptr, nbr, A1, Np);
  gemm_bf16_k<<<Np / 128, 256, 0, stream>>>(A1, B1, h, nullptr, b1l, 1);
  gemm_bf16_k<<<Np / 128, 256, 0, stream>>>(h, B2, tmat, umat, nullptr, 0);
  agg2_k<<<(N + 3) / 4, 256, 0, stream>>>(tmat, umat, rowptr, nbr, b2l, out, N);
}

// Round 9
// 251.528 us; speedup vs baseline: 5.9305x; 1.0482x over previous
//
#include <hip/hip_runtime.h>
#include <hip/hip_bf16.h>

typedef __bf16 bf16;
typedef __attribute__((ext_vector_type(8))) __bf16 bf16x8;
typedef __attribute__((ext_vector_type(4))) float f32x4;

#define NBLK 256  // radix chunks == scanA block size (bucket-aligned scan)

// unpack 8 packed bf16 (uint4) -> two f32x4
__device__ inline void unpack8(uint4 r, f32x4& a, f32x4& b) {
  a.x = __uint_as_float(r.x << 16);
  a.y = __uint_as_float(r.x & 0xffff0000u);
  a.z = __uint_as_float(r.y << 16);
  a.w = __uint_as_float(r.y & 0xffff0000u);
  b.x = __uint_as_float(r.z << 16);
  b.y = __uint_as_float(r.z & 0xffff0000u);
  b.z = __uint_as_float(r.w << 16);
  b.w = __uint_as_float(r.w & 0xffff0000u);
}

// predicated 8-rows-per-wave slot load: slot q = lane>>3, 8 lanes cover a 128 B row
__device__ inline uint4 slot_load(const bf16* __restrict__ tab, const int* __restrict__ nbr,
                                  int base, int e, int q, int fo) {
  int idx = base + q;
  uint4 r = make_uint4(0u, 0u, 0u, 0u);
  if (idx < e) {
    int j = nbr[idx];
    r = *(const uint4*)(tab + j * 64 + fo);
  }
  return r;
}

// Fused setup: blocks [0,NBLK) histogram; [NBLK,NBLK+128) pack B1/B2; rest cvt x->xb.
__global__ __launch_bounds__(256) void setup_k(const float* __restrict__ x,
                                               const int* __restrict__ dst,
                                               const float* __restrict__ W1l,
                                               const float* __restrict__ W1r,
                                               const float* __restrict__ W2l,
                                               const float* __restrict__ W2r,
                                               bf16* __restrict__ xb,
                                               bf16* __restrict__ B1,
                                               bf16* __restrict__ B2,
                                               int* __restrict__ hist,
                                               int E, int nb, int N, int Np) {
  __shared__ int h[1024];
  int t = threadIdx.x;
  if (blockIdx.x < NBLK) {
    // per-chunk LDS histogram -> hist[bucket * NBLK + chunk]
    for (int i = t; i < nb; i += 256) h[i] = 0;
    __syncthreads();
    int chunk = (E + NBLK - 1) / NBLK;
    int s = blockIdx.x * chunk, e = min(E, s + chunk);
    for (int i = s + t; i < e; i += 256) atomicAdd(&h[dst[i] >> 7], 1);
    __syncthreads();
    for (int i = t; i < nb; i += 256) hist[(long)i * NBLK + blockIdx.x] = h[i];
  } else if (blockIdx.x < NBLK + 128) {
    int gid = (blockIdx.x - NBLK) * 256 + t;  // 0..32767
    if (gid < 16384) {
      int c = gid >> 7, k = gid & 127;
      float v = (k < 64) ? W1l[c * 64 + k] : W1r[c * 64 + (k - 64)];
      B1[gid] = (bf16)v;
    } else {
      int idx = gid - 16384;
      int n = idx >> 7, k = idx & 127;
      float v = (n < 64) ? W2l[n * 128 + k] : W2r[(n - 64) * 128 + k];
      B2[idx] = (bf16)v;
    }
  } else {
    int gid = (blockIdx.x - NBLK - 128) * 256 + t;  // one per 4 elems
    long base = (long)gid * 4;
    if (base >= (long)Np * 64) return;
    if (base < (long)N * 64) {
      f32x4 v = *(const f32x4*)(x + base);
      bf16 o[4] = {(bf16)v.x, (bf16)v.y, (bf16)v.z, (bf16)v.w};
      *(ulong1*)(xb + base) = *(ulong1*)o;
    } else {
      bf16 o[4] = {(bf16)0.0f, (bf16)0.0f, (bf16)0.0f, (bf16)0.0f};
      *(ulong1*)(xb + base) = *(ulong1*)o;
    }
  }
}

// scanA: one block per bucket; exclusive scan of the bucket's 256 chunk counts
// in place; bucket total -> bsum[bucket].
__global__ __launch_bounds__(256) void scanA_k(int* __restrict__ hist,
                                               int* __restrict__ bsum) {
  __shared__ int sd[256];
  int t = threadIdx.x;
  int idx = blockIdx.x * 256 + t;
  int v = hist[idx];
  sd[t] = v;
  __syncthreads();
#pragma unroll
  for (int off = 1; off < 256; off <<= 1) {
    int tv = (t >= off) ? sd[t - off] : 0;
    __syncthreads();
    if (t >= off) sd[t] += tv;
    __syncthreads();
  }
  hist[idx] = sd[t] - v;  // bucket-local exclusive prefix
  if (t == 255) bsum[blockIdx.x] = sd[255];
}

// scanB: single-block in-place exclusive scan of bsum (nb <= 1024).
// Afterwards bsum[b] = global start offset of bucket b.
__global__ __launch_bounds__(1024) void scanB_k(int* __restrict__ bsum, int nb) {
  __shared__ int sd[1024];
  int t = threadIdx.x;
  int v = (t < nb) ? bsum[t] : 0;
  sd[t] = v;
  __syncthreads();
#pragma unroll
  for (int off = 1; off < 1024; off <<= 1) {
    int tv = (t >= off) ? sd[t - off] : 0;
    __syncthreads();
    if (t >= off) sd[t] += tv;
    __syncthreads();
  }
  if (t < nb) bsum[t] = sd[t] - v;
}

// Pass 2: re-read chunk, LDS cursors = bsum[b] + hist[b][chunk], write packed
// records (src<<7 | local-dst) into bucket regions.
__global__ __launch_bounds__(512) void scat_k(const int* __restrict__ src,
                                              const int* __restrict__ dst,
                                              const int* __restrict__ hist,
                                              const int* __restrict__ bsum,
                                              unsigned* __restrict__ ebuf, int E, int nb) {
  __shared__ int cur[1024];
  for (int i = threadIdx.x; i < nb; i += 512)
    cur[i] = bsum[i] + hist[(long)i * NBLK + blockIdx.x];
  __syncthreads();
  int chunk = (E + NBLK - 1) / NBLK;
  int s = blockIdx.x * chunk, e = min(E, s + chunk);
  for (int i = s + threadIdx.x; i < e; i += 512) {
    int d = dst[i];
    int pos = atomicAdd(&cur[d >> 7], 1);
    ebuf[pos] = ((unsigned)src[i] << 7) | (unsigned)(d & 127);
  }
}

// per-bucket LDS counting sort -> node-ordered nbr + rowptr.
__global__ __launch_bounds__(256) void csr_k(const unsigned* __restrict__ ebuf,
                                             const int* __restrict__ bsum,
                                             int* __restrict__ rowptr,
                                             int* __restrict__ nbr, int nb, int Np, int E) {
  __shared__ int hcnt[128];
  __shared__ int hoff[128];
  int b = blockIdx.x, t = threadIdx.x;
  int s = bsum[b];
  int e = (b + 1 < nb) ? bsum[b + 1] : E;
  if (t < 128) hcnt[t] = 0;
  __syncthreads();
  for (int i = s + t; i < e; i += 256) atomicAdd(&hcnt[ebuf[i] & 127u], 1);
  __syncthreads();
  if (t < 128) hoff[t] = hcnt[t];
  __syncthreads();
#pragma unroll
  for (int off = 1; off < 128; off <<= 1) {
    int v = (t < 128 && t >= off) ? hoff[t - off] : 0;
    __syncthreads();
    if (t < 128 && t >= off) hoff[t] += v;
    __syncthreads();
  }
  if (t < 128) {
    int ex = hoff[t] - hcnt[t];  // exclusive scan
    rowptr[b * 128 + t] = s + ex;
    hcnt[t] = ex;  // becomes relative cursor
  }
  if (blockIdx.x == gridDim.x - 1 && t == 0) rowptr[Np] = E;
  __syncthreads();
  for (int i = s + t; i < e; i += 256) {
    unsigned r = ebuf[i];
    int pos = atomicAdd(&hcnt[r & 127u], 1);
    nbr[s + pos] = (int)(r >> 7);
  }
}

// ---- layer 1: wave per node; 8 lanes/row uint4 gathers, depth-2 pipeline ----
__global__ __launch_bounds__(256) void agg1_k(const bf16* __restrict__ xb,
                                              const int* __restrict__ rowptr,
                                              const int* __restrict__ nbr,
                                              bf16* __restrict__ A1, int Np) {
  int wave = threadIdx.x >> 6, lane = threadIdx.x & 63;
  int n = blockIdx.x * 4 + wave;
  if (n >= Np) return;
  int s = rowptr[n], e = rowptr[n + 1];
  int q = lane >> 3, f = lane & 7;
  int fo = f * 8;  // 8 features per lane (16 B)
  f32x4 sa = {0, 0, 0, 0}, sb = {0, 0, 0, 0};
  uint4 c0 = slot_load(xb, nbr, s, e, q, fo);
  uint4 c1 = slot_load(xb, nbr, s + 8, e, q, fo);
  int i = s + 16;
  for (; i < e; i += 16) {
    uint4 n0 = slot_load(xb, nbr, i, e, q, fo);
    uint4 n1 = slot_load(xb, nbr, i + 8, e, q, fo);
    f32x4 a, b;
    unpack8(c0, a, b); sa += a; sb += b;
    unpack8(c1, a, b); sa += a; sb += b;
    c0 = n0; c1 = n1;
  }
  {
    f32x4 a, b;
    unpack8(c0, a, b); sa += a; sb += b;
    unpack8(c1, a, b); sa += a; sb += b;
  }
  float v[8] = {sa.x, sa.y, sa.z, sa.w, sb.x, sb.y, sb.z, sb.w};
#pragma unroll
  for (int k = 0; k < 8; k++) {
    v[k] += __shfl_xor(v[k], 8);
    v[k] += __shfl_xor(v[k], 16);
    v[k] += __shfl_xor(v[k], 32);
  }
  float invd = 1.0f / fmaxf((float)(e - s), 1.0f);
  if (q == 0) {
    bf16x8 o = {(bf16)(v[0] * invd), (bf16)(v[1] * invd), (bf16)(v[2] * invd),
                (bf16)(v[3] * invd), (bf16)(v[4] * invd), (bf16)(v[5] * invd),
                (bf16)(v[6] * invd), (bf16)(v[7] * invd)};
    *(bf16x8*)(A1 + n * 128 + fo) = o;
  } else if (q == 1) {
    uint4 rv = *(const uint4*)(xb + n * 64 + fo);  // pads: xb==0
    *(uint4*)(A1 + n * 128 + 64 + fo) = rv;
  }
}

// ---- fused GEMM1+GEMM2: h = relu(A1*B1^T + b1l) stays in LDS; C2 = h*B2^T ----
// Per block: 128 rows. GEMM1 epilogue writes h-tile to LDS (C/D layout -> row-major),
// GEMM2 reads A-fragments back. B fragments loaded per-k-step to cap VGPR.
__global__ __launch_bounds__(256) void gemm2x_k(const bf16* __restrict__ A,
                                                const bf16* __restrict__ B1,
                                                const bf16* __restrict__ B2,
                                                const float* __restrict__ b1l,
                                                bf16* __restrict__ Ct,
                                                bf16* __restrict__ Cu) {
  __shared__ bf16 hl[128][136];  // +8 pad: row stride 272 B -> bank advance 4/row
  int wave = threadIdx.x >> 6;
  int lane = threadIdx.x & 63;
  int row = lane & 15;
  int quad = lane >> 4;
  long mbase = (long)blockIdx.x * 128 + (long)wave * 32;
  int mloc = wave * 32;

  // ---- GEMM1 ----
  f32x4 acc[2][8] = {};
#pragma unroll
  for (int s = 0; s < 4; s++) {
    bf16x8 a0 = *(const bf16x8*)(A + (mbase + row) * 128 + s * 32 + quad * 8);
    bf16x8 a1 = *(const bf16x8*)(A + (mbase + 16 + row) * 128 + s * 32 + quad * 8);
#pragma unroll
    for (int j = 0; j < 8; j++) {
      bf16x8 bf = *(const bf16x8*)(B1 + (long)(j * 16 + row) * 128 + s * 32 + quad * 8);
      acc[0][j] = __builtin_amdgcn_mfma_f32_16x16x32_bf16(a0, bf, acc[0][j], 0, 0, 0);
      acc[1][j] = __builtin_amdgcn_mfma_f32_16x16x32_bf16(a1, bf, acc[1][j], 0, 0, 0);
    }
  }
  // epilogue 1: bias + relu -> LDS (C/D layout: col=j*16+row, row=quad*4+i)
#pragma unroll
  for (int r = 0; r < 2; r++) {
#pragma unroll
    for (int j = 0; j < 8; j++) {
      int col = j * 16 + row;
      float bv = b1l[col];
#pragma unroll
      for (int i = 0; i < 4; i++) {
        float v = acc[r][j][i] + bv;
        v = v > 0.0f ? v : 0.0f;
        hl[mloc + r * 16 + quad * 4 + i][col] = (bf16)v;
      }
    }
  }
  __syncthreads();

  // ---- GEMM2 ----
  f32x4 acc2[2][8] = {};
#pragma unroll
  for (int s = 0; s < 4; s++) {
    bf16x8 a0 = *(const bf16x8*)(&hl[mloc + row][s * 32 + quad * 8]);
    bf16x8 a1 = *(const bf16x8*)(&hl[mloc + 16 + row][s * 32 + quad * 8]);
#pragma unroll
    for (int j = 0; j < 8; j++) {
      bf16x8 bf = *(const bf16x8*)(B2 + (long)(j * 16 + row) * 128 + s * 32 + quad * 8);
      acc2[0][j] = __builtin_amdgcn_mfma_f32_16x16x32_bf16(a0, bf, acc2[0][j], 0, 0, 0);
      acc2[1][j] = __builtin_amdgcn_mfma_f32_16x16x32_bf16(a1, bf, acc2[1][j], 0, 0, 0);
    }
  }
  // epilogue 2: split store cols 0..63 -> Ct, 64..127 -> Cu (ld 64 each)
#pragma unroll
  for (int r = 0; r < 2; r++) {
    long rb = mbase + r * 16;
#pragma unroll
    for (int j = 0; j < 8; j++) {
      int col = j * 16 + row;
#pragma unroll
      for (int i = 0; i < 4; i++) {
        float v = acc2[r][j][i];
        long mrow = rb + quad * 4 + i;
        if (col < 64) Ct[mrow * 64 + col] = (bf16)v;
        else Cu[mrow * 64 + (col - 64)] = (bf16)v;
      }
    }
  }
}

// ---- layer 2: wave per node; 8 lanes/row uint4 gathers; fused bias+root+out ----
__global__ __launch_bounds__(256) void agg2_k(const bf16* __restrict__ tmat,
                                              const bf16* __restrict__ umat,
                                              const int* __restrict__ rowptr,
                                              const int* __restrict__ nbr,
                                              const float* __restrict__ b2l,
                                              float* __restrict__ out, int N) {
  int wave = threadIdx.x >> 6, lane = threadIdx.x & 63;
  int n = blockIdx.x * 4 + wave;
  if (n >= N) return;
  int s = rowptr[n], e = rowptr[n + 1];
  int q = lane >> 3, f = lane & 7;
  int fo = f * 8;
  f32x4 sa = {0, 0, 0, 0}, sb = {0, 0, 0, 0};
  uint4 c0 = slot_load(tmat, nbr, s, e, q, fo);
  uint4 c1 = slot_load(tmat, nbr, s + 8, e, q, fo);
  int i = s + 16;
  for (; i < e; i += 16) {
    uint4 n0 = slot_load(tmat, nbr, i, e, q, fo);
    uint4 n1 = slot_load(tmat, nbr, i + 8, e, q, fo);
    f32x4 a, b;
    unpack8(c0, a, b); sa += a; sb += b;
    unpack8(c1, a, b); sa += a; sb += b;
    c0 = n0; c1 = n1;
  }
  {
    f32x4 a, b;
    unpack8(c0, a, b); sa += a; sb += b;
    unpack8(c1, a, b); sa += a; sb += b;
  }
  float v[8] = {sa.x, sa.y, sa.z, sa.w, sb.x, sb.y, sb.z, sb.w};
#pragma unroll
  for (int k = 0; k < 8; k++) {
    v[k] += __shfl_xor(v[k], 8);
    v[k] += __shfl_xor(v[k], 16);
    v[k] += __shfl_xor(v[k], 32);
  }
  if (q == 0) {
    float invd = 1.0f / fmaxf((float)(e - s), 1.0f);
    f32x4 b0 = *(const f32x4*)(b2l + fo);
    f32x4 b1 = *(const f32x4*)(b2l + fo + 4);
    f32x4 ua, ub;
    unpack8(*(const uint4*)(umat + n * 64 + fo), ua, ub);
    f32x4 o0, o1;
    o0.x = v[0] * invd + b0.x + ua.x;
    o0.y = v[1] * invd + b0.y + ua.y;
    o0.z = v[2] * invd + b0.z + ua.z;
    o0.w = v[3] * invd + b0.w + ua.w;
    o1.x = v[4] * invd + b1.x + ub.x;
    o1.y = v[5] * invd + b1.y + ub.y;
    o1.z = v[6] * invd + b1.z + ub.z;
    o1.w = v[7] * invd + b1.w + ub.w;
    *(f32x4*)(out + n * 64 + fo) = o0;
    *(f32x4*)(out + n * 64 + fo + 4) = o1;
  }
}

static inline size_t align256(size_t x) { return (x + 255) / 256 * 256; }

extern "C" void kernel_launch(void* const* d_in, const int* in_sizes, int n_in,
                              void* d_out, int out_size, void* d_ws, size_t ws_size,
                              hipStream_t stream) {
  const float* x = (const float*)d_in[0];
  const int* edge_index = (const int*)d_in[1];
  const float* W1l = (const float*)d_in[2];
  const float* b1l = (const float*)d_in[3];
  const float* W1r = (const float*)d_in[4];
  const float* W2l = (const float*)d_in[5];
  const float* b2l = (const float*)d_in[6];
  const float* W2r = (const float*)d_in[7];

  const int N = in_sizes[0] / 64;        // 100000
  const int E = in_sizes[1] / 2;         // 1200000
  const int Np = (N + 127) / 128 * 128;  // 100096
  const int nb = Np / 128;               // 782 buckets (<=1024 for scanB)
  const int M = nb * NBLK;               // hist elements (200192)

  const int* src = edge_index;
  const int* dst = edge_index + E;

  // ws layout (~75 MB; must not alias: gemm2x reads A1 while writing tmat/umat)
  char* ws = (char*)d_ws;
  size_t off = 0;
  int* hist = (int*)(ws + off);           off += align256((size_t)M * 4);
  int* bsum = (int*)(ws + off);           off += align256((size_t)nb * 4);
  int* rowptr = (int*)(ws + off);         off += align256((size_t)(Np + 1) * 4);
  unsigned* ebuf = (unsigned*)(ws + off); off += align256((size_t)E * 4);
  int* nbr = (int*)(ws + off);            off += align256((size_t)E * 4);
  bf16* xb = (bf16*)(ws + off);           off += align256((size_t)Np * 64 * 2);
  bf16* A1 = (bf16*)(ws + off);           off += align256((size_t)Np * 128 * 2);
  bf16* tmat = (bf16*)(ws + off);         off += align256((size_t)Np * 64 * 2);
  bf16* umat = (bf16*)(ws + off);         off += align256((size_t)Np * 64 * 2);
  bf16* B1 = (bf16*)(ws + off);           off += align256(128 * 128 * 2);
  bf16* B2 = (bf16*)(ws + off);           off += align256(128 * 128 * 2);
  float* out = (float*)d_out;

  const int cvtBlocks = (int)(((long)Np * 64 / 4 + 255) / 256);
  setup_k<<<NBLK + 128 + cvtBlocks, 256, 0, stream>>>(x, dst, W1l, W1r, W2l, W2r,
                                                      xb, B1, B2, hist, E, nb, N, Np);
  scanA_k<<<nb, 256, 0, stream>>>(hist, bsum);
  scanB_k<<<1, 1024, 0, stream>>>(bsum, nb);
  scat_k<<<NBLK, 512, 0, stream>>>(src, dst, hist, bsum, ebuf, E, nb);
  csr_k<<<nb, 256, 0, stream>>>(ebuf, bsum, rowptr, nbr, nb, Np, E);

  agg1_k<<<Np / 4, 256, 0, stream>>>(xb, rowptr, nbr, A1, Np);
  gemm2x_k<<<Np / 128, 256, 0, stream>>>(A1, B1, B2, b1l, tmat, umat);
  agg2_k<<<(N + 3) / 4, 256, 0, stream>>>(tmat, umat, rowptr, nbr, b2l, out, N);
}